// Round 2
// baseline (1488.660 us; speedup 1.0000x reference)
//
#include <hip/hip_runtime.h>
#include <hip/hip_bf16.h>

// Problem constants
#define BB 2
#define SS 2048
#define DD 128
#define HH 8
#define HDIM 16
#define DF 512  // 4*D

__device__ __forceinline__ float wsum(float v) {
#pragma unroll
  for (int off = 32; off > 0; off >>= 1) v += __shfl_down(v, off, 64);
  return v;
}
__device__ __forceinline__ float wmaxr(float v) {
#pragma unroll
  for (int off = 32; off > 0; off >>= 1) v = fmaxf(v, __shfl_down(v, off, 64));
  return v;
}

// X: (B*S, D) fp32 row-major. W: (D, D) fp32. Out: fp32 in (B,H,S,HD) layout,
// absorbing the _split quirk: col c -> head h = c&7, dim d = c>>3.
__global__ __launch_bounds__(128) void proj_kernel(const float* __restrict__ X,
                                                   const float* __restrict__ W,
                                                   float* __restrict__ Out) {
  const int m = blockIdx.x;          // 0..B*S-1
  const int n = threadIdx.x;         // 0..127  (output column)
  const int b = m / SS, s = m % SS;
  __shared__ float xs[DD];
  xs[n] = X[(size_t)m * DD + n];
  __syncthreads();
  float acc = 0.f;
#pragma unroll 8
  for (int k = 0; k < DD; k++) acc += xs[k] * W[k * DD + n];
  const int h = n & 7, d = n >> 3;
  Out[(((size_t)(b * HH + h)) * SS + s) * HDIM + d] = acc;
}

// Q,K,V: fp32 (B,H,S,HD). Out: fp32 (B,S,D) pre-merged (col = d*8+h).
__global__ __launch_bounds__(256) void attn_kernel(const float* __restrict__ Q,
                                                   const float* __restrict__ K,
                                                   const float* __restrict__ V,
                                                   float* __restrict__ Out) {
  const int qi = blockIdx.x, h = blockIdx.y, b = blockIdx.z;
  const int t = threadIdx.x, lane = t & 63, wid = t >> 6;
  __shared__ float red[16];
  __shared__ float red2[64];

  const size_t headoff = ((size_t)(b * HH + h)) * SS;
  const float* qrow = Q + (headoff + qi) * HDIM;
  const float4 q0 = ((const float4*)qrow)[0];
  const float4 q1 = ((const float4*)qrow)[1];
  const float4 q2 = ((const float4*)qrow)[2];
  const float4 q3 = ((const float4*)qrow)[3];

  const float* kbase = K + headoff * HDIM;
  float scv[8];
  float lmax = -1e30f;
#pragma unroll
  for (int i = 0; i < 8; i++) {
    const int k = t + i * 256;
    const float4* kr = (const float4*)(kbase + (size_t)k * HDIM);
    const float4 k0 = kr[0], k1 = kr[1], k2 = kr[2], k3 = kr[3];
    float dot = q0.x * k0.x + q0.y * k0.y + q0.z * k0.z + q0.w * k0.w
              + q1.x * k1.x + q1.y * k1.y + q1.z * k1.z + q1.w * k1.w
              + q2.x * k2.x + q2.y * k2.y + q2.z * k2.z + q2.w * k2.w
              + q3.x * k3.x + q3.y * k3.y + q3.z * k3.z + q3.w * k3.w;
    dot *= 0.25f;  // 1/sqrt(HD=16)
    scv[i] = dot;
    lmax = fmaxf(lmax, dot);
  }
  const float wm = wmaxr(lmax);
  if (lane == 0) red[wid] = wm;
  __syncthreads();
  const float bmax = fmaxf(fmaxf(red[0], red[1]), fmaxf(red[2], red[3]));

  float lsum = 0.f;
#pragma unroll
  for (int i = 0; i < 8; i++) {
    scv[i] = __expf(scv[i] - bmax);
    lsum += scv[i];
  }
  const float wsv = wsum(lsum);
  if (lane == 0) red[8 + wid] = wsv;
  __syncthreads();
  const float inv = 1.f / (red[8] + red[9] + red[10] + red[11]);

  const float* vbase = V + headoff * HDIM;
  float acc[16];
#pragma unroll
  for (int d = 0; d < 16; d++) acc[d] = 0.f;
#pragma unroll
  for (int i = 0; i < 8; i++) {
    const int k = t + i * 256;
    const float p = scv[i];
    const float4* vr = (const float4*)(vbase + (size_t)k * HDIM);
    const float4 v0 = vr[0], v1 = vr[1], v2 = vr[2], v3 = vr[3];
    acc[0] += p * v0.x; acc[1] += p * v0.y; acc[2] += p * v0.z; acc[3] += p * v0.w;
    acc[4] += p * v1.x; acc[5] += p * v1.y; acc[6] += p * v1.z; acc[7] += p * v1.w;
    acc[8] += p * v2.x; acc[9] += p * v2.y; acc[10] += p * v2.z; acc[11] += p * v2.w;
    acc[12] += p * v3.x; acc[13] += p * v3.y; acc[14] += p * v3.z; acc[15] += p * v3.w;
  }
#pragma unroll
  for (int d = 0; d < 16; d++) acc[d] = wsum(acc[d]);
  if (lane == 0) {
#pragma unroll
    for (int d = 0; d < 16; d++) red2[wid * 16 + d] = acc[d];
  }
  __syncthreads();
  if (t < 16) {
    const float o = (red2[t] + red2[16 + t] + red2[32 + t] + red2[48 + t]) * inv;
    // merge: Out[b, qi, d*8 + h]
    Out[((size_t)b * SS + qi) * DD + t * HH + h] = o;
  }
}

// Out = A @ W + bias + residual (all fp32).
__global__ __launch_bounds__(128) void gemm_res_kernel(const float* __restrict__ A,
                                                       const float* __restrict__ W,
                                                       const float* __restrict__ bias,
                                                       const float* __restrict__ res,
                                                       float* __restrict__ Out) {
  const int m = blockIdx.x;
  const int n = threadIdx.x;
  __shared__ float xs[DD];
  xs[n] = A[(size_t)m * DD + n];
  __syncthreads();
  float acc = bias[n];
#pragma unroll 8
  for (int k = 0; k < DD; k++) acc += xs[k] * W[k * DD + n];
  acc += res[(size_t)m * DD + n];
  Out[(size_t)m * DD + n] = acc;
}

// y = (x - mean) / var, var unbiased (/(D-1)), NO eps, divide by var (faithful quirk).
__global__ __launch_bounds__(128) void norm_kernel(const float* __restrict__ X,
                                                   float* __restrict__ Out) {
  const int m = blockIdx.x, n = threadIdx.x, lane = n & 63, wid = n >> 6;
  __shared__ float r[4];
  const float x = X[(size_t)m * DD + n];
  const float s = wsum(x);
  if (lane == 0) r[wid] = s;
  __syncthreads();
  const float mean = (r[0] + r[1]) * (1.0f / 128.0f);
  const float c = x - mean;
  const float s2 = wsum(c * c);
  if (lane == 0) r[2 + wid] = s2;
  __syncthreads();
  const float var = (r[2] + r[3]) * (1.0f / 127.0f);
  Out[(size_t)m * DD + n] = c / var;
}

// H = relu(A @ W3 + b3); A (B*S, D), W3 (D, 4D), out (B*S, 4D), all fp32.
__global__ __launch_bounds__(512) void ffn1_kernel(const float* __restrict__ A,
                                                   const float* __restrict__ W3,
                                                   const float* __restrict__ b3,
                                                   float* __restrict__ Hout) {
  const int m = blockIdx.x;
  const int n = threadIdx.x;  // 0..511
  __shared__ float xs[DD];
  if (n < DD) xs[n] = A[(size_t)m * DD + n];
  __syncthreads();
  float acc = b3[n];
#pragma unroll 8
  for (int k = 0; k < DD; k++) acc += xs[k] * W3[(size_t)k * DF + n];
  Hout[(size_t)m * DF + n] = fmaxf(acc, 0.f);
}

// Out = H @ W4 + b4 + r2 (all fp32). H (B*S, 4D), W4 (4D, D).
__global__ __launch_bounds__(128) void ffn2_kernel(const float* __restrict__ Hin,
                                                   const float* __restrict__ W4,
                                                   const float* __restrict__ b4,
                                                   const float* __restrict__ r2,
                                                   float* __restrict__ Out) {
  const int m = blockIdx.x;
  const int n = threadIdx.x;
  __shared__ float xs[DF];
  for (int i = n; i < DF; i += DD) xs[i] = Hin[(size_t)m * DF + i];
  __syncthreads();
  float acc = b4[n];
#pragma unroll 8
  for (int k = 0; k < DF; k++) acc += xs[k] * W4[(size_t)k * DD + n];
  acc += r2[(size_t)m * DD + n];
  Out[(size_t)m * DD + n] = acc;
}

extern "C" void kernel_launch(void* const* d_in, const int* in_sizes, int n_in,
                              void* d_out, int out_size, void* d_ws, size_t ws_size,
                              hipStream_t stream) {
  (void)in_sizes; (void)n_in; (void)out_size; (void)ws_size;
  const float* x_tgt    = (const float*)d_in[0];
  const float* enc_out  = (const float*)d_in[1];
  const float* self_wq  = (const float*)d_in[2];
  const float* self_wk  = (const float*)d_in[3];
  const float* self_wv  = (const float*)d_in[4];
  const float* cross_wq = (const float*)d_in[5];
  const float* cross_wk = (const float*)d_in[6];
  const float* cross_wv = (const float*)d_in[7];
  const float* w1 = (const float*)d_in[8];
  const float* b1 = (const float*)d_in[9];
  const float* w2 = (const float*)d_in[10];
  const float* b2 = (const float*)d_in[11];
  const float* w3 = (const float*)d_in[12];
  const float* b3 = (const float*)d_in[13];
  const float* w4 = (const float*)d_in[14];
  const float* b4 = (const float*)d_in[15];
  // d_in[16], d_in[17]: masks (all ones; reference applies no mask) — unused.

  const size_t ROW = (size_t)BB * SS * DD;  // 524288 elems
  float* ws = (float*)d_ws;
  float* Qb = ws + 0 * ROW;
  float* Kb = ws + 1 * ROW;
  float* Vb = ws + 2 * ROW;
  float* AM = ws + 3 * ROW;  // merged attention out (B,S,D)
  float* R1 = ws + 4 * ROW;
  float* R2 = ws + 5 * ROW;
  float* LN = ws + 6 * ROW;
  float* Hb = ws + 7 * ROW;  // (B*S, 4D): 2M floats

  const int M = BB * SS;  // 4096
  dim3 attnGrid(SS, HH, BB);

  // ---- self attention ----
  proj_kernel<<<M, 128, 0, stream>>>(x_tgt, self_wq, Qb);
  proj_kernel<<<M, 128, 0, stream>>>(x_tgt, self_wk, Kb);
  proj_kernel<<<M, 128, 0, stream>>>(x_tgt, self_wv, Vb);
  attn_kernel<<<attnGrid, 256, 0, stream>>>(Qb, Kb, Vb, AM);
  gemm_res_kernel<<<M, 128, 0, stream>>>(AM, w1, b1, x_tgt, R1);

  // ---- cross attention: Q from enc_out, K/V from x_tgt (faithful quirk) ----
  proj_kernel<<<M, 128, 0, stream>>>(enc_out, cross_wq, Qb);
  proj_kernel<<<M, 128, 0, stream>>>(x_tgt, cross_wk, Kb);
  proj_kernel<<<M, 128, 0, stream>>>(x_tgt, cross_wv, Vb);
  attn_kernel<<<attnGrid, 256, 0, stream>>>(Qb, Kb, Vb, AM);
  gemm_res_kernel<<<M, 128, 0, stream>>>(AM, w2, b2, R1, R2);

  // ---- norm + FFN ----
  norm_kernel<<<M, 128, 0, stream>>>(R2, LN);
  ffn1_kernel<<<M, DF, 0, stream>>>(LN, w3, b3, Hb);
  ffn2_kernel<<<M, 128, 0, stream>>>(Hb, w4, b4, R2, (float*)d_out);
}

// Round 3
// 477.378 us; speedup vs baseline: 3.1184x; 3.1184x over previous
//
#include <hip/hip_runtime.h>
#include <hip/hip_bf16.h>

// Problem constants
#define BB 2
#define SS 2048
#define DD 128
#define HH 8
#define HDIM 16
#define DF 512  // 4*D
#define KSPLIT 4
#define TK 128   // keys per LDS tile

__device__ __forceinline__ float wsum(float v) {
#pragma unroll
  for (int off = 32; off > 0; off >>= 1) v += __shfl_down(v, off, 64);
  return v;
}

// X: (B*S, D) fp32 row-major. W: (D, D) fp32. Out: fp32 in (B,H,S,HD) layout,
// absorbing the _split quirk: col c -> head h = c&7, dim d = c>>3.
__global__ __launch_bounds__(128) void proj_kernel(const float* __restrict__ X,
                                                   const float* __restrict__ W,
                                                   float* __restrict__ Out) {
  const int m = blockIdx.x;          // 0..B*S-1
  const int n = threadIdx.x;         // 0..127  (output column)
  const int b = m / SS, s = m % SS;
  __shared__ float xs[DD];
  xs[n] = X[(size_t)m * DD + n];
  __syncthreads();
  float acc = 0.f;
#pragma unroll 8
  for (int k = 0; k < DD; k++) acc += xs[k] * W[k * DD + n];
  const int h = n & 7, d = n >> 3;
  Out[(((size_t)(b * HH + h)) * SS + s) * HDIM + d] = acc;
}

// Flash-style attention, no max-subtraction (scores are small by construction;
// softmax(s) == exp(s)/sum(exp(s)) exactly in infinite precision, and |s|<~10
// keeps exp well inside fp32 range).
// Grid: (SS/64, BB*HH, KSPLIT), block = 64 (one wave). Thread t owns query
// q = blockIdx.x*64+t; iterates keys [z*512, z*512+512) in 128-key LDS tiles.
// Partials: Pacc[z][bh*SS+q][16], Pl[z][bh*SS+q].
__global__ __launch_bounds__(64) void attn_flash_kernel(const float* __restrict__ Q,
                                                        const float* __restrict__ K,
                                                        const float* __restrict__ V,
                                                        float* __restrict__ Pacc,
                                                        float* __restrict__ Pl) {
  const int t = threadIdx.x;
  const int bh = blockIdx.y;           // b*8 + h
  const int z = blockIdx.z;            // key split
  const int q = blockIdx.x * 64 + t;

  __shared__ float4 sK[TK * 4];        // 128 keys x 16 floats
  __shared__ float4 sV[TK * 4];

  const size_t headoff = (size_t)bh * SS;          // rows
  const float4* Q4 = (const float4*)Q;
  const float4* K4 = (const float4*)K;
  const float4* V4 = (const float4*)V;

  // load + pre-scale q by 1/sqrt(HD)=0.25
  float4 q0 = Q4[(headoff + q) * 4 + 0];
  float4 q1 = Q4[(headoff + q) * 4 + 1];
  float4 q2 = Q4[(headoff + q) * 4 + 2];
  float4 q3 = Q4[(headoff + q) * 4 + 3];
  q0.x *= 0.25f; q0.y *= 0.25f; q0.z *= 0.25f; q0.w *= 0.25f;
  q1.x *= 0.25f; q1.y *= 0.25f; q1.z *= 0.25f; q1.w *= 0.25f;
  q2.x *= 0.25f; q2.y *= 0.25f; q2.z *= 0.25f; q2.w *= 0.25f;
  q3.x *= 0.25f; q3.y *= 0.25f; q3.z *= 0.25f; q3.w *= 0.25f;

  float4 a0 = {0, 0, 0, 0}, a1 = {0, 0, 0, 0}, a2 = {0, 0, 0, 0}, a3 = {0, 0, 0, 0};
  float l = 0.f;

  const int keybase = z * (SS / KSPLIT);  // z*512

#pragma unroll 1
  for (int kt = 0; kt < (SS / KSPLIT) / TK; kt++) {  // 4 tiles
    const size_t tilebase4 = (headoff + keybase + kt * TK) * 4;  // float4 units
    __syncthreads();
#pragma unroll
    for (int i = 0; i < 8; i++) {
      sK[t + i * 64] = K4[tilebase4 + t + i * 64];
      sV[t + i * 64] = V4[tilebase4 + t + i * 64];
    }
    __syncthreads();
#pragma unroll 2
    for (int j = 0; j < TK; j++) {
      const float4 k0 = sK[j * 4 + 0], k1 = sK[j * 4 + 1];
      const float4 k2 = sK[j * 4 + 2], k3 = sK[j * 4 + 3];
      float d0 = q0.x * k0.x + q0.y * k0.y + q0.z * k0.z + q0.w * k0.w;
      float d1 = q1.x * k1.x + q1.y * k1.y + q1.z * k1.z + q1.w * k1.w;
      float d2 = q2.x * k2.x + q2.y * k2.y + q2.z * k2.z + q2.w * k2.w;
      float d3 = q3.x * k3.x + q3.y * k3.y + q3.z * k3.z + q3.w * k3.w;
      const float p = __expf((d0 + d1) + (d2 + d3));
      l += p;
      const float4 v0 = sV[j * 4 + 0], v1 = sV[j * 4 + 1];
      const float4 v2 = sV[j * 4 + 2], v3 = sV[j * 4 + 3];
      a0.x += p * v0.x; a0.y += p * v0.y; a0.z += p * v0.z; a0.w += p * v0.w;
      a1.x += p * v1.x; a1.y += p * v1.y; a1.z += p * v1.z; a1.w += p * v1.w;
      a2.x += p * v2.x; a2.y += p * v2.y; a2.z += p * v2.z; a2.w += p * v2.w;
      a3.x += p * v3.x; a3.y += p * v3.y; a3.z += p * v3.z; a3.w += p * v3.w;
    }
  }

  float4* P4 = (float4*)Pacc;
  const size_t prow = ((size_t)z * (16 * SS) + headoff + q) * 4;
  P4[prow + 0] = a0; P4[prow + 1] = a1; P4[prow + 2] = a2; P4[prow + 3] = a3;
  Pl[(size_t)z * (16 * SS) + headoff + q] = l;
}

// Combine KSPLIT partials and write merged (B,S,D) with col = d*8+h.
__global__ __launch_bounds__(256) void attn_combine_kernel(const float* __restrict__ Pacc,
                                                           const float* __restrict__ Pl,
                                                           float* __restrict__ Out) {
  const int gid = blockIdx.x * 256 + threadIdx.x;  // (bh*SS+q)*16 + d
  const int bhq = gid >> 4;
  const int d = gid & 15;
  float num = 0.f, den = 0.f;
#pragma unroll
  for (int z = 0; z < KSPLIT; z++) {
    num += Pacc[(size_t)z * (16 * SS * 16) + gid];
    den += Pl[(size_t)z * (16 * SS) + bhq];
  }
  const int bh = bhq >> 11, q = bhq & (SS - 1);
  const int b = bh >> 3, h = bh & 7;
  Out[((size_t)b * SS + q) * DD + d * 8 + h] = num / den;
}

// Out = A @ W + bias + residual (all fp32).
__global__ __launch_bounds__(128) void gemm_res_kernel(const float* __restrict__ A,
                                                       const float* __restrict__ W,
                                                       const float* __restrict__ bias,
                                                       const float* __restrict__ res,
                                                       float* __restrict__ Out) {
  const int m = blockIdx.x;
  const int n = threadIdx.x;
  __shared__ float xs[DD];
  xs[n] = A[(size_t)m * DD + n];
  __syncthreads();
  float acc = bias[n];
#pragma unroll 8
  for (int k = 0; k < DD; k++) acc += xs[k] * W[k * DD + n];
  acc += res[(size_t)m * DD + n];
  Out[(size_t)m * DD + n] = acc;
}

// y = (x - mean) / var, var unbiased (/(D-1)), NO eps, divide by var (faithful quirk).
__global__ __launch_bounds__(128) void norm_kernel(const float* __restrict__ X,
                                                   float* __restrict__ Out) {
  const int m = blockIdx.x, n = threadIdx.x, lane = n & 63, wid = n >> 6;
  __shared__ float r[4];
  const float x = X[(size_t)m * DD + n];
  const float s = wsum(x);
  if (lane == 0) r[wid] = s;
  __syncthreads();
  const float mean = (r[0] + r[1]) * (1.0f / 128.0f);
  const float c = x - mean;
  const float s2 = wsum(c * c);
  if (lane == 0) r[2 + wid] = s2;
  __syncthreads();
  const float var = (r[2] + r[3]) * (1.0f / 127.0f);
  Out[(size_t)m * DD + n] = c / var;
}

// H = relu(A @ W3 + b3); A (B*S, D), W3 (D, 4D), out (B*S, 4D), all fp32.
__global__ __launch_bounds__(512) void ffn1_kernel(const float* __restrict__ A,
                                                   const float* __restrict__ W3,
                                                   const float* __restrict__ b3,
                                                   float* __restrict__ Hout) {
  const int m = blockIdx.x;
  const int n = threadIdx.x;  // 0..511
  __shared__ float xs[DD];
  if (n < DD) xs[n] = A[(size_t)m * DD + n];
  __syncthreads();
  float acc = b3[n];
#pragma unroll 8
  for (int k = 0; k < DD; k++) acc += xs[k] * W3[(size_t)k * DF + n];
  Hout[(size_t)m * DF + n] = fmaxf(acc, 0.f);
}

// Out = H @ W4 + b4 + r2 (all fp32). H (B*S, 4D), W4 (4D, D).
__global__ __launch_bounds__(128) void ffn2_kernel(const float* __restrict__ Hin,
                                                   const float* __restrict__ W4,
                                                   const float* __restrict__ b4,
                                                   const float* __restrict__ r2,
                                                   float* __restrict__ Out) {
  const int m = blockIdx.x;
  const int n = threadIdx.x;
  __shared__ float xs[DF];
  for (int i = n; i < DF; i += DD) xs[i] = Hin[(size_t)m * DF + i];
  __syncthreads();
  float acc = b4[n];
#pragma unroll 8
  for (int k = 0; k < DF; k++) acc += xs[k] * W4[(size_t)k * DD + n];
  acc += r2[(size_t)m * DD + n];
  Out[(size_t)m * DD + n] = acc;
}

extern "C" void kernel_launch(void* const* d_in, const int* in_sizes, int n_in,
                              void* d_out, int out_size, void* d_ws, size_t ws_size,
                              hipStream_t stream) {
  (void)in_sizes; (void)n_in; (void)out_size; (void)ws_size;
  const float* x_tgt    = (const float*)d_in[0];
  const float* enc_out  = (const float*)d_in[1];
  const float* self_wq  = (const float*)d_in[2];
  const float* self_wk  = (const float*)d_in[3];
  const float* self_wv  = (const float*)d_in[4];
  const float* cross_wq = (const float*)d_in[5];
  const float* cross_wk = (const float*)d_in[6];
  const float* cross_wv = (const float*)d_in[7];
  const float* w1 = (const float*)d_in[8];
  const float* b1 = (const float*)d_in[9];
  const float* w2 = (const float*)d_in[10];
  const float* b2 = (const float*)d_in[11];
  const float* w3 = (const float*)d_in[12];
  const float* b3 = (const float*)d_in[13];
  const float* w4 = (const float*)d_in[14];
  const float* b4 = (const float*)d_in[15];
  // d_in[16], d_in[17]: masks (all ones; reference applies no mask) — unused.

  const size_t ROW = (size_t)BB * SS * DD;  // 524288 elems
  float* ws = (float*)d_ws;
  float* Qb = ws + 0 * ROW;
  float* Kb = ws + 1 * ROW;
  float* Vb = ws + 2 * ROW;
  float* AM = ws + 3 * ROW;  // merged attention out (B,S,D)
  float* R1 = ws + 4 * ROW;
  float* R2 = ws + 5 * ROW;
  float* LN = ws + 6 * ROW;  // also overlays attn partials (dead by norm time)
  float* Hb = ws + 7 * ROW;  // (B*S, 4D): 2M floats
  // Attention partials overlay the LN+Hb region (only live between
  // attn_flash and attn_combine; LN/Hb only live after).
  float* Pacc = ws + 6 * ROW;                        // 4*16*2048*16 = 2.10M floats
  float* Pl   = Pacc + (size_t)KSPLIT * 16 * SS * 16;  // 131K floats (< LN+Hb extent)

  const int M = BB * SS;  // 4096
  dim3 attnGrid(SS / 64, BB * HH, KSPLIT);
  const int combBlocks = (16 * SS * 16) / 256;  // 2048

  // ---- self attention ----
  proj_kernel<<<M, 128, 0, stream>>>(x_tgt, self_wq, Qb);
  proj_kernel<<<M, 128, 0, stream>>>(x_tgt, self_wk, Kb);
  proj_kernel<<<M, 128, 0, stream>>>(x_tgt, self_wv, Vb);
  attn_flash_kernel<<<attnGrid, 64, 0, stream>>>(Qb, Kb, Vb, Pacc, Pl);
  attn_combine_kernel<<<combBlocks, 256, 0, stream>>>(Pacc, Pl, AM);
  gemm_res_kernel<<<M, 128, 0, stream>>>(AM, w1, b1, x_tgt, R1);

  // ---- cross attention: Q from enc_out, K/V from x_tgt (faithful quirk) ----
  proj_kernel<<<M, 128, 0, stream>>>(enc_out, cross_wq, Qb);
  proj_kernel<<<M, 128, 0, stream>>>(x_tgt, cross_wk, Kb);
  proj_kernel<<<M, 128, 0, stream>>>(x_tgt, cross_wv, Vb);
  attn_flash_kernel<<<attnGrid, 64, 0, stream>>>(Qb, Kb, Vb, Pacc, Pl);
  attn_combine_kernel<<<combBlocks, 256, 0, stream>>>(Pacc, Pl, AM);
  gemm_res_kernel<<<M, 128, 0, stream>>>(AM, w2, b2, R1, R2);

  // ---- norm + FFN ----
  norm_kernel<<<M, 128, 0, stream>>>(R2, LN);
  ffn1_kernel<<<M, DF, 0, stream>>>(LN, w3, b3, Hb);
  ffn2_kernel<<<M, 128, 0, stream>>>(Hb, w4, b4, R2, (float*)d_out);
}

// Round 4
// 335.935 us; speedup vs baseline: 4.4314x; 1.4210x over previous
//
#include <hip/hip_runtime.h>
#include <hip/hip_bf16.h>

// Problem constants
#define BB 2
#define SS 2048
#define DD 128
#define HH 8
#define HDIM 16
#define DF 512  // 4*D

// attention tiling
#define QT 64         // queries per block (4 waves x 16)
#define KT 64         // keys per LDS tile
#define SK_STRIDE 48  // bf16 units; 96B rows, 16B aligned
#define SVT_STRIDE 72 // 144B rows
#define SP_STRIDE 72  // 144B rows

typedef float floatx4 __attribute__((ext_vector_type(4)));
typedef short frag8 __attribute__((ext_vector_type(8)));

__device__ __forceinline__ float wsum(float v) {
#pragma unroll
  for (int off = 32; off > 0; off >>= 1) v += __shfl_down(v, off, 64);
  return v;
}

__device__ __forceinline__ short f2bf(float x) {
  __hip_bfloat16 h = __float2bfloat16(x);
  return *reinterpret_cast<short*>(&h);
}

// X: (B*S, D) fp32. W: (D, D) fp32. Out: fp32 (B,H,S,HD), absorbing the
// _split quirk: col c -> head h = c&7, dim d = c>>3.
__global__ __launch_bounds__(128) void proj_kernel(const float* __restrict__ X,
                                                   const float* __restrict__ W,
                                                   float* __restrict__ Out) {
  const int m = blockIdx.x;
  const int n = threadIdx.x;
  const int b = m / SS, s = m % SS;
  __shared__ float xs[DD];
  xs[n] = X[(size_t)m * DD + n];
  __syncthreads();
  float acc = 0.f;
#pragma unroll 8
  for (int k = 0; k < DD; k++) acc += xs[k] * W[k * DD + n];
  const int h = n & 7, d = n >> 3;
  Out[(((size_t)(b * HH + h)) * SS + s) * HDIM + d] = acc;
}

// V-projection writing TRANSPOSED per-head layout: (B,H,HD,S).
__global__ __launch_bounds__(128) void proj_v_kernel(const float* __restrict__ X,
                                                     const float* __restrict__ W,
                                                     float* __restrict__ Out) {
  const int m = blockIdx.x;
  const int n = threadIdx.x;
  const int b = m / SS, s = m % SS;
  __shared__ float xs[DD];
  xs[n] = X[(size_t)m * DD + n];
  __syncthreads();
  float acc = 0.f;
#pragma unroll 8
  for (int k = 0; k < DD; k++) acc += xs[k] * W[k * DD + n];
  const int h = n & 7, d = n >> 3;
  Out[(((size_t)(b * HH + h)) * HDIM + d) * SS + s] = acc;
}

// MFMA flash attention (no max-subtraction; scores small by construction).
// Q,K: fp32 (B,H,S,HD). Vt: fp32 (B,H,HD,S). Out: fp32 (B,S,D), col = d*8+h.
// Grid (SS/QT, BB*HH), block 256 (4 waves x 16 queries).
__global__ __launch_bounds__(256) void attn_mfma_kernel(const float* __restrict__ Q,
                                                        const float* __restrict__ K,
                                                        const float* __restrict__ Vt,
                                                        float* __restrict__ Out) {
  const int t = threadIdx.x;
  const int wid = t >> 6, lane = t & 63;
  const int quad = lane >> 4, l16 = lane & 15;
  const int bh = blockIdx.y;
  const int qbase = blockIdx.x * QT;
  const size_t headoff = (size_t)bh * SS;

  __shared__ short sK[KT * SK_STRIDE];          // [key][48] bf16; cols 16..31 zeroed
  __shared__ short sVt[HDIM * SVT_STRIDE];      // [dim][72] bf16
  __shared__ short sP[4][16 * SP_STRIDE];       // per wave [q][72] bf16

  // zero the padded K columns 16..31 (read by quads 2,3; never re-staged)
  for (int idx = t; idx < KT * 16; idx += 256) {
    const int key = idx >> 4, c = idx & 15;
    sK[key * SK_STRIDE + 16 + c] = 0;
  }

  // Q fragment: A[m=q16=l16][k=quad*8+j]; quads 2,3 hold the zero-padded K range.
  const int q = qbase + wid * 16 + l16;
  frag8 qf;
  if (quad < 2) {
    const float* qrow = Q + (headoff + q) * HDIM + quad * 8;
    const float4 a = ((const float4*)qrow)[0];
    const float4 b = ((const float4*)qrow)[1];
    qf[0] = f2bf(a.x * 0.25f); qf[1] = f2bf(a.y * 0.25f);
    qf[2] = f2bf(a.z * 0.25f); qf[3] = f2bf(a.w * 0.25f);
    qf[4] = f2bf(b.x * 0.25f); qf[5] = f2bf(b.y * 0.25f);
    qf[6] = f2bf(b.z * 0.25f); qf[7] = f2bf(b.w * 0.25f);
  } else {
#pragma unroll
    for (int i = 0; i < 8; i++) qf[i] = 0;
  }

  frag8 onef;
#pragma unroll
  for (int i = 0; i < 8; i++) onef[i] = (short)0x3f80;  // bf16 1.0

  floatx4 acc_o = {0.f, 0.f, 0.f, 0.f};
  floatx4 acc_l = {0.f, 0.f, 0.f, 0.f};

  const int skey = t >> 2, sc4 = t & 3;    // K staging: key 0..63, chunk 0..3
  const int sdim = t >> 4, vc4 = t & 15;   // V staging: dim 0..15, chunk 0..15
  const float4* K4 = (const float4*)K;
  const float4* V4 = (const float4*)Vt;

#pragma unroll 1
  for (int kt = 0; kt < SS / KT; kt++) {
    const int keybase = kt * KT;
    __syncthreads();  // previous tile fully consumed
    {
      // stage K tile: 64 keys x 16 hd
      const float4 kv = K4[((headoff + keybase + skey) << 2) + sc4];
      short4 ks;
      ks.x = f2bf(kv.x); ks.y = f2bf(kv.y); ks.z = f2bf(kv.z); ks.w = f2bf(kv.w);
      *(short4*)&sK[skey * SK_STRIDE + sc4 * 4] = ks;
      // stage Vt tile: 16 dims x 64 keys
      const float4 vv = V4[((((size_t)bh * HDIM + sdim) * SS + keybase) >> 2) + vc4];
      short4 vs;
      vs.x = f2bf(vv.x); vs.y = f2bf(vv.y); vs.z = f2bf(vv.z); vs.w = f2bf(vv.w);
      *(short4*)&sVt[sdim * SVT_STRIDE + vc4 * 4] = vs;
    }
    __syncthreads();

    // QK^T: 4 key-subtiles of 16. B-frag: n=key=l16, k=quad*8+j from sK.
    floatx4 sc[4];
#pragma unroll
    for (int st = 0; st < 4; st++) {
      const frag8 kf = *(const frag8*)&sK[(st * 16 + l16) * SK_STRIDE + quad * 8];
      const floatx4 z = {0.f, 0.f, 0.f, 0.f};
      sc[st] = __builtin_amdgcn_mfma_f32_16x16x32_bf16(qf, kf, z, 0, 0, 0);
    }

    // exp + store P[q16][key] (bf16) into this wave's sP
#pragma unroll
    for (int st = 0; st < 4; st++) {
#pragma unroll
      for (int r = 0; r < 4; r++) {
        const float p = __expf(sc[st][r]);
        sP[wid][(quad * 4 + r) * SP_STRIDE + st * 16 + l16] = f2bf(p);
      }
    }
    // (within-wave LDS write->read ordering handled by compiler waitcnt; sP is wave-private)

    // PV (operand-swapped): C[d][q] += Vt(16d x 64k) @ P^T(64k x 16q)
#pragma unroll
    for (int w = 0; w < 2; w++) {
      const frag8 vf = *(const frag8*)&sVt[l16 * SVT_STRIDE + w * 32 + quad * 8];
      const frag8 pf = *(const frag8*)&sP[wid][l16 * SP_STRIDE + w * 32 + quad * 8];
      acc_o = __builtin_amdgcn_mfma_f32_16x16x32_bf16(vf, pf, acc_o, 0, 0, 0);
      acc_l = __builtin_amdgcn_mfma_f32_16x16x32_bf16(onef, pf, acc_l, 0, 0, 0);
    }
  }

  // Epilogue: acc_o reg r = O'[d=quad*4+r][q16=l16]; acc_l any reg = l[q16=l16].
  const int b = bh >> 3, h = bh & 7;
  const float linv = 1.f / acc_l[0];
#pragma unroll
  for (int r = 0; r < 4; r++) {
    const int d = quad * 4 + r;
    Out[((size_t)b * SS + q) * DD + d * 8 + h] = acc_o[r] * linv;
  }
}

// Out = A @ W + bias + residual (all fp32).
__global__ __launch_bounds__(128) void gemm_res_kernel(const float* __restrict__ A,
                                                       const float* __restrict__ W,
                                                       const float* __restrict__ bias,
                                                       const float* __restrict__ res,
                                                       float* __restrict__ Out) {
  const int m = blockIdx.x;
  const int n = threadIdx.x;
  __shared__ float xs[DD];
  xs[n] = A[(size_t)m * DD + n];
  __syncthreads();
  float acc = bias[n];
#pragma unroll 8
  for (int k = 0; k < DD; k++) acc += xs[k] * W[k * DD + n];
  acc += res[(size_t)m * DD + n];
  Out[(size_t)m * DD + n] = acc;
}

// y = (x - mean) / var, var unbiased (/(D-1)), NO eps (faithful quirk).
__global__ __launch_bounds__(128) void norm_kernel(const float* __restrict__ X,
                                                   float* __restrict__ Out) {
  const int m = blockIdx.x, n = threadIdx.x, lane = n & 63, wid = n >> 6;
  __shared__ float r[4];
  const float x = X[(size_t)m * DD + n];
  const float s = wsum(x);
  if (lane == 0) r[wid] = s;
  __syncthreads();
  const float mean = (r[0] + r[1]) * (1.0f / 128.0f);
  const float c = x - mean;
  const float s2 = wsum(c * c);
  if (lane == 0) r[2 + wid] = s2;
  __syncthreads();
  const float var = (r[2] + r[3]) * (1.0f / 127.0f);
  Out[(size_t)m * DD + n] = c / var;
}

// H = relu(A @ W3 + b3)
__global__ __launch_bounds__(512) void ffn1_kernel(const float* __restrict__ A,
                                                   const float* __restrict__ W3,
                                                   const float* __restrict__ b3,
                                                   float* __restrict__ Hout) {
  const int m = blockIdx.x;
  const int n = threadIdx.x;
  __shared__ float xs[DD];
  if (n < DD) xs[n] = A[(size_t)m * DD + n];
  __syncthreads();
  float acc = b3[n];
#pragma unroll 8
  for (int k = 0; k < DD; k++) acc += xs[k] * W3[(size_t)k * DF + n];
  Hout[(size_t)m * DF + n] = fmaxf(acc, 0.f);
}

// Out = H @ W4 + b4 + r2
__global__ __launch_bounds__(128) void ffn2_kernel(const float* __restrict__ Hin,
                                                   const float* __restrict__ W4,
                                                   const float* __restrict__ b4,
                                                   const float* __restrict__ r2,
                                                   float* __restrict__ Out) {
  const int m = blockIdx.x;
  const int n = threadIdx.x;
  __shared__ float xs[DF];
  for (int i = n; i < DF; i += DD) xs[i] = Hin[(size_t)m * DF + i];
  __syncthreads();
  float acc = b4[n];
#pragma unroll 8
  for (int k = 0; k < DF; k++) acc += xs[k] * W4[(size_t)k * DD + n];
  acc += r2[(size_t)m * DD + n];
  Out[(size_t)m * DD + n] = acc;
}

extern "C" void kernel_launch(void* const* d_in, const int* in_sizes, int n_in,
                              void* d_out, int out_size, void* d_ws, size_t ws_size,
                              hipStream_t stream) {
  (void)in_sizes; (void)n_in; (void)out_size; (void)ws_size;
  const float* x_tgt    = (const float*)d_in[0];
  const float* enc_out  = (const float*)d_in[1];
  const float* self_wq  = (const float*)d_in[2];
  const float* self_wk  = (const float*)d_in[3];
  const float* self_wv  = (const float*)d_in[4];
  const float* cross_wq = (const float*)d_in[5];
  const float* cross_wk = (const float*)d_in[6];
  const float* cross_wv = (const float*)d_in[7];
  const float* w1 = (const float*)d_in[8];
  const float* b1 = (const float*)d_in[9];
  const float* w2 = (const float*)d_in[10];
  const float* b2 = (const float*)d_in[11];
  const float* w3 = (const float*)d_in[12];
  const float* b3 = (const float*)d_in[13];
  const float* w4 = (const float*)d_in[14];
  const float* b4 = (const float*)d_in[15];
  // d_in[16], d_in[17]: masks (all ones; reference applies no mask) — unused.

  const size_t ROW = (size_t)BB * SS * DD;  // 524288 elems
  float* ws = (float*)d_ws;
  float* Qb = ws + 0 * ROW;
  float* Kb = ws + 1 * ROW;
  float* Vb = ws + 2 * ROW;  // transposed per-head (B,H,HD,S)
  float* AM = ws + 3 * ROW;  // merged attention out (B,S,D)
  float* R1 = ws + 4 * ROW;
  float* R2 = ws + 5 * ROW;
  float* LN = ws + 6 * ROW;
  float* Hb = ws + 7 * ROW;  // (B*S, 4D)

  const int M = BB * SS;  // 4096
  dim3 attnGrid(SS / QT, BB * HH);

  // ---- self attention ----
  proj_kernel<<<M, 128, 0, stream>>>(x_tgt, self_wq, Qb);
  proj_kernel<<<M, 128, 0, stream>>>(x_tgt, self_wk, Kb);
  proj_v_kernel<<<M, 128, 0, stream>>>(x_tgt, self_wv, Vb);
  attn_mfma_kernel<<<attnGrid, 256, 0, stream>>>(Qb, Kb, Vb, AM);
  gemm_res_kernel<<<M, 128, 0, stream>>>(AM, w1, b1, x_tgt, R1);

  // ---- cross attention: Q from enc_out, K/V from x_tgt (faithful quirk) ----
  proj_kernel<<<M, 128, 0, stream>>>(enc_out, cross_wq, Qb);
  proj_kernel<<<M, 128, 0, stream>>>(x_tgt, cross_wk, Kb);
  proj_v_kernel<<<M, 128, 0, stream>>>(x_tgt, cross_wv, Vb);
  attn_mfma_kernel<<<attnGrid, 256, 0, stream>>>(Qb, Kb, Vb, AM);
  gemm_res_kernel<<<M, 128, 0, stream>>>(AM, w2, b2, R1, R2);

  // ---- norm + FFN ----
  norm_kernel<<<M, 128, 0, stream>>>(R2, LN);
  ffn1_kernel<<<M, DF, 0, stream>>>(LN, w3, b3, Hb);
  ffn2_kernel<<<M, 128, 0, stream>>>(Hb, w4, b4, R2, (float*)d_out);
}

// Round 5
// 269.195 us; speedup vs baseline: 5.5301x; 1.2479x over previous
//
#include <hip/hip_runtime.h>
#include <hip/hip_bf16.h>

// Problem constants
#define BB 2
#define SS 2048
#define DD 128
#define HH 8
#define HDIM 16
#define DF 512
#define SP_STRIDE 72  // bf16 units; 144B rows

typedef float floatx4 __attribute__((ext_vector_type(4)));
typedef short frag8 __attribute__((ext_vector_type(8)));

__device__ __forceinline__ short f2bf(float x) {
  union { __hip_bfloat16 h; short s; } u;
  u.h = __float2bfloat16(x);
  return u.s;
}
__device__ __forceinline__ frag8 cvt8(const float4 a, const float4 b) {
  frag8 r;
  r[0] = f2bf(a.x); r[1] = f2bf(a.y); r[2] = f2bf(a.z); r[3] = f2bf(a.w);
  r[4] = f2bf(b.x); r[5] = f2bf(b.y); r[6] = f2bf(b.z); r[7] = f2bf(b.w);
  return r;
}

// ---------------- weight prep: WT[n][k] bf16, scale folded ----------------
struct WSrc { const float* p[10]; };
// order: self_wq,self_wk,self_wv,cross_wq,cross_wk,cross_wv,w1,w2,w3,w4
__global__ __launch_bounds__(256) void wprep_kernel(WSrc w, short* __restrict__ dst) {
  const int wi = blockIdx.y;
  const int kshift = (wi == 9) ? 9 : 7;          // K: 512 for w4, else 128
  const int N = (wi == 8) ? 512 : 128;           // w3 has N=512
  const int total = N << kshift;
  const int offs[10] = {0, 16384, 32768, 49152, 65536, 81920, 98304, 114688, 131072, 196608};
  const float sc = (wi == 0 || wi == 3) ? 0.25f : 1.0f;  // fold 1/sqrt(HD) into Wq
  const float* src = w.p[wi];
  short* d = dst + offs[wi];
  const int K = 1 << kshift;
  for (int idx = blockIdx.x * 256 + threadIdx.x; idx < total; idx += gridDim.x * 256) {
    const int n = idx >> kshift, k = idx & (K - 1);
    d[idx] = f2bf(src[k * N + n] * sc);
  }
}

// ---------------- fused QKV projection (MFMA) ----------------
// grid (M/16, 3), block 64 (1 wave). which: 0=Q (A=Aq), 1=K, 2=Vt (A=Akv).
// Writes bf16: Q,K (B,H,S,HD); Vt (B,H,HD,S). _split quirk: h=n&7, d=n>>3.
__global__ __launch_bounds__(64) void qkv_kernel(const float* __restrict__ Aq,
                                                 const float* __restrict__ Akv,
                                                 const short* __restrict__ wt,
                                                 short* __restrict__ Qb,
                                                 short* __restrict__ Kb,
                                                 short* __restrict__ Vtb) {
  const int lane = threadIdx.x, quad = lane >> 4, l16 = lane & 15;
  const int mbase = blockIdx.x * 16;
  const int which = blockIdx.y;
  const float* A = (which == 0) ? Aq : Akv;
  const short* W = wt + which * 16384;

  floatx4 acc[8];
#pragma unroll
  for (int ct = 0; ct < 8; ct++) acc[ct] = (floatx4){0.f, 0.f, 0.f, 0.f};

#pragma unroll
  for (int ks = 0; ks < 4; ks++) {
    const float4* ar = (const float4*)&A[(size_t)(mbase + l16) * DD + ks * 32 + quad * 8];
    const frag8 af = cvt8(ar[0], ar[1]);
#pragma unroll
    for (int ct = 0; ct < 8; ct++) {
      const frag8 bf = *(const frag8*)&W[(ct * 16 + l16) * DD + ks * 32 + quad * 8];
      acc[ct] = __builtin_amdgcn_mfma_f32_16x16x32_bf16(af, bf, acc[ct], 0, 0, 0);
    }
  }

  const int b = mbase >> 11;                 // m / 2048
  const int sbase = (mbase & 2047) + quad * 4;
#pragma unroll
  for (int ct = 0; ct < 8; ct++) {
    const int n = ct * 16 + l16, h = n & 7, dci = n >> 3;
    const int bh = b * HH + h;
#pragma unroll
    for (int r = 0; r < 4; r++) {
      const int s = sbase + r;
      const short v = f2bf(acc[ct][r]);
      if (which == 0)      Qb[((size_t)bh * SS + s) * HDIM + dci] = v;
      else if (which == 1) Kb[((size_t)bh * SS + s) * HDIM + dci] = v;
      else                 Vtb[((size_t)bh * HDIM + dci) * SS + s] = v;
    }
  }
}

// ---------------- MFMA flash attention, all-global bf16 operands ----------------
// Q,K: bf16 (B,H,S,HD) (Q pre-scaled). Vt: bf16 (B,H,HD,S). AM: bf16 (B,S,D), col=d*8+h.
// grid (SS/16, BB*HH), block 64 (1 wave, 16 queries). No __syncthreads anywhere.
__global__ __launch_bounds__(64) void attn_mfma_kernel(const short* __restrict__ Q,
                                                       const short* __restrict__ K,
                                                       const short* __restrict__ Vt,
                                                       short* __restrict__ AM) {
  const int lane = threadIdx.x, quad = lane >> 4, l16 = lane & 15;
  const int bh = blockIdx.y;
  const int qbase = blockIdx.x * 16;
  const int q = qbase + l16;
  const size_t headoff = (size_t)bh * SS;

  __shared__ short sP[16 * SP_STRIDE];

  // Q fragment: A[m=l16][k=quad*8+j]; quads 2,3 are the zero-padded K range (HD=16 -> K=32).
  frag8 qf;
  if (quad < 2) qf = *(const frag8*)&Q[(headoff + q) * HDIM + quad * 8];
  else {
#pragma unroll
    for (int i = 0; i < 8; i++) qf[i] = 0;
  }

  frag8 onef;
#pragma unroll
  for (int i = 0; i < 8; i++) onef[i] = (short)0x3f80;  // bf16 1.0

  floatx4 acc_o = {0.f, 0.f, 0.f, 0.f};
  floatx4 acc_l = {0.f, 0.f, 0.f, 0.f};

#pragma unroll 1
  for (int kt = 0; kt < SS / 64; kt++) {
    const int keybase = kt * 64;
    // QK^T over 4 key-subtiles: B-frag n=key=l16, k=quad*8+j direct from global.
    floatx4 sc[4];
#pragma unroll
    for (int st = 0; st < 4; st++) {
      frag8 kf;
      if (quad < 2) kf = *(const frag8*)&K[(headoff + keybase + st * 16 + l16) * HDIM + quad * 8];
      else {
#pragma unroll
        for (int i = 0; i < 8; i++) kf[i] = 0;
      }
      const floatx4 z = {0.f, 0.f, 0.f, 0.f};
      sc[st] = __builtin_amdgcn_mfma_f32_16x16x32_bf16(qf, kf, z, 0, 0, 0);
    }
    // exp (no max-subtraction: scores small by construction) -> sP[q16][key]
#pragma unroll
    for (int st = 0; st < 4; st++) {
#pragma unroll
      for (int r = 0; r < 4; r++) {
        sP[(quad * 4 + r) * SP_STRIDE + st * 16 + l16] = f2bf(__expf(sc[st][r]));
      }
    }
    // PV (operand-swapped): C[d][q] += Vt(16d x 64k) @ P^T; A-frag from global Vt, B-frag from sP.
#pragma unroll
    for (int w = 0; w < 2; w++) {
      const frag8 vf = *(const frag8*)&Vt[((size_t)bh * HDIM + l16) * SS + keybase + w * 32 + quad * 8];
      const frag8 pf = *(const frag8*)&sP[l16 * SP_STRIDE + w * 32 + quad * 8];
      acc_o = __builtin_amdgcn_mfma_f32_16x16x32_bf16(vf, pf, acc_o, 0, 0, 0);
      acc_l = __builtin_amdgcn_mfma_f32_16x16x32_bf16(onef, pf, acc_l, 0, 0, 0);
    }
  }

  // acc_o reg r = O'[d=quad*4+r][q=l16]; acc_l[0] = l[q=l16] (rows replicated).
  const int b = bh >> 3, h = bh & 7;
  const float linv = 1.f / acc_l[0];
#pragma unroll
  for (int r = 0; r < 4; r++) {
    const int d = quad * 4 + r;
    AM[((size_t)b * SS + q) * DD + d * 8 + h] = f2bf(acc_o[r] * linv);
  }
}

// ---------------- attention-output GEMM + bias + residual (+ fused norm) ----------------
// A bf16 (M,128), W bf16 [n][128], res fp32, Out fp32; if NORM also LN bf16 = (v-mean)/var.
template <bool NORM>
__global__ __launch_bounds__(64) void gemm_res_mfma(const short* __restrict__ A,
                                                    const short* __restrict__ W,
                                                    const float* __restrict__ bias,
                                                    const float* __restrict__ res,
                                                    float* __restrict__ Out,
                                                    short* __restrict__ LN) {
  const int lane = threadIdx.x, quad = lane >> 4, l16 = lane & 15;
  const int mbase = blockIdx.x * 16;

  floatx4 acc[8];
#pragma unroll
  for (int ct = 0; ct < 8; ct++) acc[ct] = (floatx4){0.f, 0.f, 0.f, 0.f};

#pragma unroll
  for (int ks = 0; ks < 4; ks++) {
    const frag8 af = *(const frag8*)&A[(size_t)(mbase + l16) * DD + ks * 32 + quad * 8];
#pragma unroll
    for (int ct = 0; ct < 8; ct++) {
      const frag8 bf = *(const frag8*)&W[(ct * 16 + l16) * DD + ks * 32 + quad * 8];
      acc[ct] = __builtin_amdgcn_mfma_f32_16x16x32_bf16(af, bf, acc[ct], 0, 0, 0);
    }
  }

  float v[8][4];
#pragma unroll
  for (int ct = 0; ct < 8; ct++) {
    const int n = ct * 16 + l16;
    const float bn = bias[n];
#pragma unroll
    for (int r = 0; r < 4; r++) {
      const int m = mbase + quad * 4 + r;
      v[ct][r] = acc[ct][r] + bn + res[(size_t)m * DD + n];
      Out[(size_t)m * DD + n] = v[ct][r];
    }
  }

  if (NORM) {
#pragma unroll
    for (int r = 0; r < 4; r++) {
      float rs = 0.f;
#pragma unroll
      for (int ct = 0; ct < 8; ct++) rs += v[ct][r];
#pragma unroll
      for (int m = 1; m < 16; m <<= 1) rs += __shfl_xor(rs, m, 64);
      const float mean = rs * (1.0f / 128.0f);
      float cs = 0.f;
#pragma unroll
      for (int ct = 0; ct < 8; ct++) {
        const float c = v[ct][r] - mean;
        cs += c * c;
      }
#pragma unroll
      for (int m = 1; m < 16; m <<= 1) cs += __shfl_xor(cs, m, 64);
      const float inv_var = 127.0f / cs;  // divide by var (faithful quirk), var = cs/127
      const int mm = mbase + quad * 4 + r;
#pragma unroll
      for (int ct = 0; ct < 8; ct++) {
        const int n = ct * 16 + l16;
        LN[(size_t)mm * DD + n] = f2bf((v[ct][r] - mean) * inv_var);
      }
    }
  }
}

// ---------------- FFN1: Hb = relu(LN @ W3 + b3), bf16 out ----------------
// grid (M/16, 4): blockIdx.y selects 128-col slab of the 512 outputs.
__global__ __launch_bounds__(64) void ffn1_mfma(const short* __restrict__ A,
                                                const short* __restrict__ W,  // w3T [n][128], n<512
                                                const float* __restrict__ b3,
                                                short* __restrict__ Hb) {
  const int lane = threadIdx.x, quad = lane >> 4, l16 = lane & 15;
  const int mbase = blockIdx.x * 16;
  const int nblk = blockIdx.y * 128;

  floatx4 acc[8];
#pragma unroll
  for (int ct = 0; ct < 8; ct++) acc[ct] = (floatx4){0.f, 0.f, 0.f, 0.f};

#pragma unroll
  for (int ks = 0; ks < 4; ks++) {
    const frag8 af = *(const frag8*)&A[(size_t)(mbase + l16) * DD + ks * 32 + quad * 8];
#pragma unroll
    for (int ct = 0; ct < 8; ct++) {
      const frag8 bf = *(const frag8*)&W[(size_t)(nblk + ct * 16 + l16) * DD + ks * 32 + quad * 8];
      acc[ct] = __builtin_amdgcn_mfma_f32_16x16x32_bf16(af, bf, acc[ct], 0, 0, 0);
    }
  }

#pragma unroll
  for (int ct = 0; ct < 8; ct++) {
    const int n = nblk + ct * 16 + l16;
    const float bn = b3[n];
#pragma unroll
    for (int r = 0; r < 4; r++) {
      const int m = mbase + quad * 4 + r;
      Hb[(size_t)m * DF + n] = f2bf(fmaxf(acc[ct][r] + bn, 0.f));
    }
  }
}

// ---------------- FFN2: out = Hb @ W4 + b4 + R2 (fp32 out) ----------------
__global__ __launch_bounds__(64) void ffn2_mfma(const short* __restrict__ A,  // Hb bf16 (M,512)
                                                const short* __restrict__ W,  // w4T [n][512]
                                                const float* __restrict__ b4,
                                                const float* __restrict__ res,
                                                float* __restrict__ Out) {
  const int lane = threadIdx.x, quad = lane >> 4, l16 = lane & 15;
  const int mbase = blockIdx.x * 16;

  floatx4 acc[8];
#pragma unroll
  for (int ct = 0; ct < 8; ct++) acc[ct] = (floatx4){0.f, 0.f, 0.f, 0.f};

#pragma unroll 4
  for (int ks = 0; ks < 16; ks++) {
    const frag8 af = *(const frag8*)&A[(size_t)(mbase + l16) * DF + ks * 32 + quad * 8];
#pragma unroll
    for (int ct = 0; ct < 8; ct++) {
      const frag8 bf = *(const frag8*)&W[(size_t)(ct * 16 + l16) * DF + ks * 32 + quad * 8];
      acc[ct] = __builtin_amdgcn_mfma_f32_16x16x32_bf16(af, bf, acc[ct], 0, 0, 0);
    }
  }

#pragma unroll
  for (int ct = 0; ct < 8; ct++) {
    const int n = ct * 16 + l16;
    const float bn = b4[n];
#pragma unroll
    for (int r = 0; r < 4; r++) {
      const int m = mbase + quad * 4 + r;
      Out[(size_t)m * DD + n] = acc[ct][r] + bn + res[(size_t)m * DD + n];
    }
  }
}

extern "C" void kernel_launch(void* const* d_in, const int* in_sizes, int n_in,
                              void* d_out, int out_size, void* d_ws, size_t ws_size,
                              hipStream_t stream) {
  (void)in_sizes; (void)n_in; (void)out_size; (void)ws_size;
  const float* x_tgt   = (const float*)d_in[0];
  const float* enc_out = (const float*)d_in[1];
  const float* b1 = (const float*)d_in[9];
  const float* b2 = (const float*)d_in[11];
  const float* b3 = (const float*)d_in[13];
  const float* b4 = (const float*)d_in[15];

  WSrc wsrc;
  wsrc.p[0] = (const float*)d_in[2];   // self_wq
  wsrc.p[1] = (const float*)d_in[3];   // self_wk
  wsrc.p[2] = (const float*)d_in[4];   // self_wv
  wsrc.p[3] = (const float*)d_in[5];   // cross_wq
  wsrc.p[4] = (const float*)d_in[6];   // cross_wk
  wsrc.p[5] = (const float*)d_in[7];   // cross_wv
  wsrc.p[6] = (const float*)d_in[8];   // w1
  wsrc.p[7] = (const float*)d_in[10];  // w2
  wsrc.p[8] = (const float*)d_in[12];  // w3
  wsrc.p[9] = (const float*)d_in[14];  // w4

  // workspace layout (float-slot offsets; bf16 buffers use 2 elems per slot)
  float* ws = (float*)d_ws;
  short* wt  = (short*)(ws + 0);          // 262144 bf16 (512 KB)
  short* Qb  = (short*)(ws + 131072);     // 524288 bf16
  short* Kb  = (short*)(ws + 393216);
  short* Vtb = (short*)(ws + 655360);
  short* AM  = (short*)(ws + 917504);
  float* R1  = ws + 1179648;
  float* R2  = ws + 1703936;
  short* LN  = (short*)(ws + 2228224);    // 524288 bf16
  short* Hb  = (short*)(ws + 2490368);    // 2097152 bf16

  const int M = BB * SS;  // 4096
  const int MT = M / 16;  // 256 row-tiles

  wprep_kernel<<<dim3(64, 10), 256, 0, stream>>>(wsrc, wt);

  // ---- self attention ----
  qkv_kernel<<<dim3(MT, 3), 64, 0, stream>>>(x_tgt, x_tgt, wt, Qb, Kb, Vtb);
  attn_mfma_kernel<<<dim3(SS / 16, BB * HH), 64, 0, stream>>>(Qb, Kb, Vtb, AM);
  gemm_res_mfma<false><<<MT, 64, 0, stream>>>(AM, wt + 98304, b1, x_tgt, R1, nullptr);

  // ---- cross attention: Q from enc_out, K/V from x_tgt (faithful quirk) ----
  qkv_kernel<<<dim3(MT, 3), 64, 0, stream>>>(enc_out, x_tgt, wt + 49152, Qb, Kb, Vtb);
  attn_mfma_kernel<<<dim3(SS / 16, BB * HH), 64, 0, stream>>>(Qb, Kb, Vtb, AM);
  gemm_res_mfma<true><<<MT, 64, 0, stream>>>(AM, wt + 114688, b2, R1, R2, LN);

  // ---- FFN ----
  ffn1_mfma<<<dim3(MT, 4), 64, 0, stream>>>(LN, wt + 131072, b3, Hb);
  ffn2_mfma<<<MT, 64, 0, stream>>>(Hb, wt + 196608, b4, R2, (float*)d_out);
}

// Round 6
// 201.824 us; speedup vs baseline: 7.3760x; 1.3338x over previous
//
#include <hip/hip_runtime.h>
#include <hip/hip_bf16.h>

// Problem constants
#define BB 2
#define SS 2048
#define DD 128
#define HH 8
#define HDIM 16
#define DF 512
#define SP_STRIDE 72  // bf16 units; 144B rows

typedef float floatx4 __attribute__((ext_vector_type(4)));
typedef short frag8 __attribute__((ext_vector_type(8)));

__device__ __forceinline__ short f2bf(float x) {
  union { __hip_bfloat16 h; short s; } u;
  u.h = __float2bfloat16(x);
  return u.s;
}
__device__ __forceinline__ frag8 cvt8(const float4 a, const float4 b) {
  frag8 r;
  r[0] = f2bf(a.x); r[1] = f2bf(a.y); r[2] = f2bf(a.z); r[3] = f2bf(a.w);
  r[4] = f2bf(b.x); r[5] = f2bf(b.y); r[6] = f2bf(b.z); r[7] = f2bf(b.w);
  return r;
}

// ---------------- weight prep: WT[n][k] bf16, scale folded ----------------
struct WSrc { const float* p[10]; };
// order: self_wq,self_wk,self_wv,cross_wq,cross_wk,cross_wv,w1,w2,w3,w4
__global__ __launch_bounds__(256) void wprep_kernel(WSrc w, short* __restrict__ dst) {
  const int wi = blockIdx.y;
  const int kshift = (wi == 9) ? 9 : 7;          // K: 512 for w4, else 128
  const int N = (wi == 8) ? 512 : 128;           // w3 has N=512
  const int total = N << kshift;
  const int offs[10] = {0, 16384, 32768, 49152, 65536, 81920, 98304, 114688, 131072, 196608};
  const float sc = (wi == 0 || wi == 3) ? 0.25f : 1.0f;  // fold 1/sqrt(HD) into Wq
  const float* src = w.p[wi];
  short* d = dst + offs[wi];
  const int K = 1 << kshift;
  for (int idx = blockIdx.x * 256 + threadIdx.x; idx < total; idx += gridDim.x * 256) {
    const int n = idx >> kshift, k = idx & (K - 1);
    d[idx] = f2bf(src[k * N + n] * sc);
  }
}

// ---------------- fused 6-way QKV projection (MFMA) ----------------
// grid (M/16, 6), block 64 (1 wave). blockIdx.y: 0..2 self QKV (A=x_tgt),
// 3 cross Q (A=enc_out, quirk), 4..5 cross K/V (A=x_tgt).
// Writes bf16: Q,K (B,H,S,HD) (Q pre-scaled via wprep); Vt (B,H,HD,S).
// _split quirk: h=n&7, d=n>>3.
__global__ __launch_bounds__(64) void qkv_kernel(const float* __restrict__ x_tgt,
                                                 const float* __restrict__ enc_out,
                                                 const short* __restrict__ wt,
                                                 short* __restrict__ Qs, short* __restrict__ Ks,
                                                 short* __restrict__ Vts,
                                                 short* __restrict__ Qc, short* __restrict__ Kc,
                                                 short* __restrict__ Vtc) {
  const int lane = threadIdx.x, quad = lane >> 4, l16 = lane & 15;
  const int mbase = blockIdx.x * 16;
  const int which = blockIdx.y;
  const int kind = which % 3;  // 0=Q,1=K,2=Vt
  const float* A = (which == 3) ? enc_out : x_tgt;
  const short* W = wt + which * 16384;
  short* Qb = (which < 3) ? Qs : Qc;
  short* Kb = (which < 3) ? Ks : Kc;
  short* Vtb = (which < 3) ? Vts : Vtc;

  floatx4 acc[8];
#pragma unroll
  for (int ct = 0; ct < 8; ct++) acc[ct] = (floatx4){0.f, 0.f, 0.f, 0.f};

#pragma unroll
  for (int ks = 0; ks < 4; ks++) {
    const float4* ar = (const float4*)&A[(size_t)(mbase + l16) * DD + ks * 32 + quad * 8];
    const frag8 af = cvt8(ar[0], ar[1]);
#pragma unroll
    for (int ct = 0; ct < 8; ct++) {
      const frag8 bf = *(const frag8*)&W[(ct * 16 + l16) * DD + ks * 32 + quad * 8];
      acc[ct] = __builtin_amdgcn_mfma_f32_16x16x32_bf16(af, bf, acc[ct], 0, 0, 0);
    }
  }

  const int b = mbase >> 11;
  const int sbase = (mbase & 2047) + quad * 4;
#pragma unroll
  for (int ct = 0; ct < 8; ct++) {
    const int n = ct * 16 + l16, h = n & 7, dci = n >> 3;
    const int bh = b * HH + h;
#pragma unroll
    for (int r = 0; r < 4; r++) {
      const int s = sbase + r;
      const short v = f2bf(acc[ct][r]);
      if (kind == 0)      Qb[((size_t)bh * SS + s) * HDIM + dci] = v;
      else if (kind == 1) Kb[((size_t)bh * SS + s) * HDIM + dci] = v;
      else                Vtb[((size_t)bh * HDIM + dci) * SS + s] = v;
    }
  }
}

// ---------------- MFMA flash attention, split-K 4-wave blocks ----------------
// Q,K: bf16 (B,H,S,HD) (Q pre-scaled). Vt: bf16 (B,H,HD,S). AM: bf16 (B,S,D), col=d*8+h.
// grid (SS/16, BB*HH, 2), block 256 = 4 waves; wave w owns keys [w*512, w*512+512).
// blockIdx.z selects the attention instance (0=self, 1=cross).
__global__ __launch_bounds__(256) void attn_mfma_kernel(
    const short* __restrict__ Qa, const short* __restrict__ Ka,
    const short* __restrict__ Vta, short* __restrict__ AMa,
    const short* __restrict__ Qc, const short* __restrict__ Kc,
    const short* __restrict__ Vtc, short* __restrict__ AMc) {
  const int t = threadIdx.x, wid = t >> 6, lane = t & 63;
  const int quad = lane >> 4, l16 = lane & 15;
  const int bh = blockIdx.y;
  const int qbase = blockIdx.x * 16;
  const int inst = blockIdx.z;
  const short* Q = inst ? Qc : Qa;
  const short* K = inst ? Kc : Ka;
  const short* Vt = inst ? Vtc : Vta;
  short* AM = inst ? AMc : AMa;
  const size_t headoff = (size_t)bh * SS;
  const int q = qbase + l16;

  __shared__ short sP[4][16 * SP_STRIDE];
  __shared__ float pnum[4][16 * 17];  // [wave][d*17+q] (pad 17: no 4-way bank alias)
  __shared__ float pl[4][16];

  // Q fragment: A[m=l16][k=quad*8+j]; quads 2,3 are the zero-padded K range (HD=16 -> K=32).
  frag8 qf;
  if (quad < 2) qf = *(const frag8*)&Q[(headoff + q) * HDIM + quad * 8];
  else {
#pragma unroll
    for (int i = 0; i < 8; i++) qf[i] = 0;
  }

  frag8 onef;
#pragma unroll
  for (int i = 0; i < 8; i++) onef[i] = (short)0x3f80;  // bf16 1.0

  floatx4 acc_o = {0.f, 0.f, 0.f, 0.f};
  floatx4 acc_l = {0.f, 0.f, 0.f, 0.f};

#pragma unroll 1
  for (int kt = 0; kt < 8; kt++) {
    const int keybase = wid * 512 + kt * 64;
    // QK^T over 4 key-subtiles: B-frag n=key=l16, k=quad*8+j direct from global.
    floatx4 sc[4];
#pragma unroll
    for (int st = 0; st < 4; st++) {
      frag8 kf;
      if (quad < 2) kf = *(const frag8*)&K[(headoff + keybase + st * 16 + l16) * HDIM + quad * 8];
      else {
#pragma unroll
        for (int i = 0; i < 8; i++) kf[i] = 0;
      }
      const floatx4 z = {0.f, 0.f, 0.f, 0.f};
      sc[st] = __builtin_amdgcn_mfma_f32_16x16x32_bf16(qf, kf, z, 0, 0, 0);
    }
    // exp (no max-subtraction: scores small by construction) -> sP[wid][q16][key]
#pragma unroll
    for (int st = 0; st < 4; st++) {
#pragma unroll
      for (int r = 0; r < 4; r++) {
        sP[wid][(quad * 4 + r) * SP_STRIDE + st * 16 + l16] = f2bf(__expf(sc[st][r]));
      }
    }
    // PV (operand-swapped): C[d][q] += Vt(16d x 64k) @ P^T; wave-private sP, no barrier.
#pragma unroll
    for (int w = 0; w < 2; w++) {
      const frag8 vf = *(const frag8*)&Vt[((size_t)bh * HDIM + l16) * SS + keybase + w * 32 + quad * 8];
      const frag8 pf = *(const frag8*)&sP[wid][l16 * SP_STRIDE + w * 32 + quad * 8];
      acc_o = __builtin_amdgcn_mfma_f32_16x16x32_bf16(vf, pf, acc_o, 0, 0, 0);
      acc_l = __builtin_amdgcn_mfma_f32_16x16x32_bf16(onef, pf, acc_l, 0, 0, 0);
    }
  }

  // stage per-wave partials: acc_o reg r = num[d=quad*4+r][q=l16]; acc_l rows replicated.
#pragma unroll
  for (int r = 0; r < 4; r++) pnum[wid][(quad * 4 + r) * 17 + l16] = acc_o[r];
  if (quad == 0) pl[wid][l16] = acc_l[0];
  __syncthreads();

  // combine: thread t -> (d = t>>4, q16 = t&15)
  {
    const int d = t >> 4, q16 = t & 15;
    const float num = pnum[0][d * 17 + q16] + pnum[1][d * 17 + q16] +
                      pnum[2][d * 17 + q16] + pnum[3][d * 17 + q16];
    const float l = pl[0][q16] + pl[1][q16] + pl[2][q16] + pl[3][q16];
    const int b = bh >> 3, h = bh & 7;
    AM[((size_t)b * SS + qbase + q16) * DD + d * 8 + h] = f2bf(num / l);
  }
}

// ---------------- attention-output GEMM + bias + residual (+ fused norm) ----------------
// A bf16 (M,128), W bf16 [n][128], res fp32, Out fp32; if NORM also LN bf16 = (v-mean)/var.
template <bool NORM>
__global__ __launch_bounds__(64) void gemm_res_mfma(const short* __restrict__ A,
                                                    const short* __restrict__ W,
                                                    const float* __restrict__ bias,
                                                    const float* __restrict__ res,
                                                    float* __restrict__ Out,
                                                    short* __restrict__ LN) {
  const int lane = threadIdx.x, quad = lane >> 4, l16 = lane & 15;
  const int mbase = blockIdx.x * 16;

  floatx4 acc[8];
#pragma unroll
  for (int ct = 0; ct < 8; ct++) acc[ct] = (floatx4){0.f, 0.f, 0.f, 0.f};

#pragma unroll
  for (int ks = 0; ks < 4; ks++) {
    const frag8 af = *(const frag8*)&A[(size_t)(mbase + l16) * DD + ks * 32 + quad * 8];
#pragma unroll
    for (int ct = 0; ct < 8; ct++) {
      const frag8 bf = *(const frag8*)&W[(ct * 16 + l16) * DD + ks * 32 + quad * 8];
      acc[ct] = __builtin_amdgcn_mfma_f32_16x16x32_bf16(af, bf, acc[ct], 0, 0, 0);
    }
  }

  float v[8][4];
#pragma unroll
  for (int ct = 0; ct < 8; ct++) {
    const int n = ct * 16 + l16;
    const float bn = bias[n];
#pragma unroll
    for (int r = 0; r < 4; r++) {
      const int m = mbase + quad * 4 + r;
      v[ct][r] = acc[ct][r] + bn + res[(size_t)m * DD + n];
      Out[(size_t)m * DD + n] = v[ct][r];
    }
  }

  if (NORM) {
#pragma unroll
    for (int r = 0; r < 4; r++) {
      float rs = 0.f;
#pragma unroll
      for (int ct = 0; ct < 8; ct++) rs += v[ct][r];
#pragma unroll
      for (int m = 1; m < 16; m <<= 1) rs += __shfl_xor(rs, m, 64);
      const float mean = rs * (1.0f / 128.0f);
      float cs = 0.f;
#pragma unroll
      for (int ct = 0; ct < 8; ct++) {
        const float c = v[ct][r] - mean;
        cs += c * c;
      }
#pragma unroll
      for (int m = 1; m < 16; m <<= 1) cs += __shfl_xor(cs, m, 64);
      const float inv_var = 127.0f / cs;  // divide by var (faithful quirk), var = cs/127
      const int mm = mbase + quad * 4 + r;
#pragma unroll
      for (int ct = 0; ct < 8; ct++) {
        const int n = ct * 16 + l16;
        LN[(size_t)mm * DD + n] = f2bf((v[ct][r] - mean) * inv_var);
      }
    }
  }
}

// ---------------- FFN1: Hb = relu(LN @ W3 + b3), bf16 out ----------------
__global__ __launch_bounds__(64) void ffn1_mfma(const short* __restrict__ A,
                                                const short* __restrict__ W,  // w3T [n][128]
                                                const float* __restrict__ b3,
                                                short* __restrict__ Hb) {
  const int lane = threadIdx.x, quad = lane >> 4, l16 = lane & 15;
  const int mbase = blockIdx.x * 16;
  const int nblk = blockIdx.y * 128;

  floatx4 acc[8];
#pragma unroll
  for (int ct = 0; ct < 8; ct++) acc[ct] = (floatx4){0.f, 0.f, 0.f, 0.f};

#pragma unroll
  for (int ks = 0; ks < 4; ks++) {
    const frag8 af = *(const frag8*)&A[(size_t)(mbase + l16) * DD + ks * 32 + quad * 8];
#pragma unroll
    for (int ct = 0; ct < 8; ct++) {
      const frag8 bf = *(const frag8*)&W[(size_t)(nblk + ct * 16 + l16) * DD + ks * 32 + quad * 8];
      acc[ct] = __builtin_amdgcn_mfma_f32_16x16x32_bf16(af, bf, acc[ct], 0, 0, 0);
    }
  }

#pragma unroll
  for (int ct = 0; ct < 8; ct++) {
    const int n = nblk + ct * 16 + l16;
    const float bn = b3[n];
#pragma unroll
    for (int r = 0; r < 4; r++) {
      const int m = mbase + quad * 4 + r;
      Hb[(size_t)m * DF + n] = f2bf(fmaxf(acc[ct][r] + bn, 0.f));
    }
  }
}

// ---------------- FFN2: out = Hb @ W4 + b4 + R2 (fp32 out) ----------------
__global__ __launch_bounds__(64) void ffn2_mfma(const short* __restrict__ A,  // Hb bf16 (M,512)
                                                const short* __restrict__ W,  // w4T [n][512]
                                                const float* __restrict__ b4,
                                                const float* __restrict__ res,
                                                float* __restrict__ Out) {
  const int lane = threadIdx.x, quad = lane >> 4, l16 = lane & 15;
  const int mbase = blockIdx.x * 16;

  floatx4 acc[8];
#pragma unroll
  for (int ct = 0; ct < 8; ct++) acc[ct] = (floatx4){0.f, 0.f, 0.f, 0.f};

#pragma unroll 4
  for (int ks = 0; ks < 16; ks++) {
    const frag8 af = *(const frag8*)&A[(size_t)(mbase + l16) * DF + ks * 32 + quad * 8];
#pragma unroll
    for (int ct = 0; ct < 8; ct++) {
      const frag8 bf = *(const frag8*)&W[(size_t)(ct * 16 + l16) * DF + ks * 32 + quad * 8];
      acc[ct] = __builtin_amdgcn_mfma_f32_16x16x32_bf16(af, bf, acc[ct], 0, 0, 0);
    }
  }

#pragma unroll
  for (int ct = 0; ct < 8; ct++) {
    const int n = ct * 16 + l16;
    const float bn = b4[n];
#pragma unroll
    for (int r = 0; r < 4; r++) {
      const int m = mbase + quad * 4 + r;
      Out[(size_t)m * DD + n] = acc[ct][r] + bn + res[(size_t)m * DD + n];
    }
  }
}

extern "C" void kernel_launch(void* const* d_in, const int* in_sizes, int n_in,
                              void* d_out, int out_size, void* d_ws, size_t ws_size,
                              hipStream_t stream) {
  (void)in_sizes; (void)n_in; (void)out_size; (void)ws_size;
  const float* x_tgt   = (const float*)d_in[0];
  const float* enc_out = (const float*)d_in[1];
  const float* b1 = (const float*)d_in[9];
  const float* b2 = (const float*)d_in[11];
  const float* b3 = (const float*)d_in[13];
  const float* b4 = (const float*)d_in[15];

  WSrc wsrc;
  wsrc.p[0] = (const float*)d_in[2];   // self_wq
  wsrc.p[1] = (const float*)d_in[3];   // self_wk
  wsrc.p[2] = (const float*)d_in[4];   // self_wv
  wsrc.p[3] = (const float*)d_in[5];   // cross_wq
  wsrc.p[4] = (const float*)d_in[6];   // cross_wk
  wsrc.p[5] = (const float*)d_in[7];   // cross_wv
  wsrc.p[6] = (const float*)d_in[8];   // w1
  wsrc.p[7] = (const float*)d_in[10];  // w2
  wsrc.p[8] = (const float*)d_in[12];  // w3
  wsrc.p[9] = (const float*)d_in[14];  // w4

  // workspace layout (float-slot offsets; bf16 buffers use 2 elems per slot)
  float* ws = (float*)d_ws;
  short* wt   = (short*)(ws + 0);          // 262144 bf16 (512 KB)
  short* Qs   = (short*)(ws + 131072);     // each QKV buf: 524288 bf16
  short* Ks   = (short*)(ws + 393216);
  short* Vts  = (short*)(ws + 655360);
  short* AMs  = (short*)(ws + 917504);
  short* Qc   = (short*)(ws + 1179648);
  short* Kc   = (short*)(ws + 1441792);
  short* Vtc  = (short*)(ws + 1703936);
  short* AMc  = (short*)(ws + 1966080);
  float* R1   = ws + 2228224;
  float* R2   = ws + 2752512;
  short* LN   = (short*)(ws + 3276800);    // 524288 bf16
  short* Hb   = (short*)(ws + 3538944);    // 2097152 bf16

  const int M = BB * SS;  // 4096
  const int MT = M / 16;  // 256 row-tiles

  wprep_kernel<<<dim3(64, 10), 256, 0, stream>>>(wsrc, wt);

  // all 6 projections in one launch (cross-Q reads enc_out — faithful quirk)
  qkv_kernel<<<dim3(MT, 6), 64, 0, stream>>>(x_tgt, enc_out, wt, Qs, Ks, Vts, Qc, Kc, Vtc);

  // both attentions in one launch (independent); split-K 4-wave blocks
  attn_mfma_kernel<<<dim3(SS / 16, BB * HH, 2), 256, 0, stream>>>(
      Qs, Ks, Vts, AMs, Qc, Kc, Vtc, AMc);

  // residual GEMMs (sequential dependency)
  gemm_res_mfma<false><<<MT, 64, 0, stream>>>(AMs, wt + 98304, b1, x_tgt, R1, nullptr);
  gemm_res_mfma<true><<<MT, 64, 0, stream>>>(AMc, wt + 114688, b2, R1, R2, LN);

  // FFN
  ffn1_mfma<<<dim3(MT, 4), 64, 0, stream>>>(LN, wt + 131072, b3, Hb);
  ffn2_mfma<<<MT, 64, 0, stream>>>(Hb, wt + 196608, b4, R2, (float*)d_out);
}

// Round 7
// 186.455 us; speedup vs baseline: 7.9840x; 1.0824x over previous
//
#include <hip/hip_runtime.h>
#include <hip/hip_bf16.h>

// Problem constants
#define BB 2
#define SS 2048
#define DD 128
#define HH 8
#define HDIM 16
#define DF 512
#define SP_STRIDE 72  // bf16 units; 144B rows
#define HS 520        // ffn LDS h stride (512 + 8 pad)

typedef float floatx4 __attribute__((ext_vector_type(4)));
typedef short frag8 __attribute__((ext_vector_type(8)));

__device__ __forceinline__ short f2bf(float x) {
  union { __hip_bfloat16 h; short s; } u;
  u.h = __float2bfloat16(x);
  return u.s;
}
__device__ __forceinline__ frag8 cvt8(const float4 a, const float4 b) {
  frag8 r;
  r[0] = f2bf(a.x); r[1] = f2bf(a.y); r[2] = f2bf(a.z); r[3] = f2bf(a.w);
  r[4] = f2bf(b.x); r[5] = f2bf(b.y); r[6] = f2bf(b.z); r[7] = f2bf(b.w);
  return r;
}

// ---------------- weight prep: WT[n][k] bf16, scale folded ----------------
struct WSrc { const float* p[10]; };
// order: self_wq,self_wk,self_wv,cross_wq,cross_wk,cross_wv,w1,w2,w3,w4
__global__ __launch_bounds__(256) void wprep_kernel(WSrc w, short* __restrict__ dst) {
  const int wi = blockIdx.y;
  const int kshift = (wi == 9) ? 9 : 7;          // K: 512 for w4, else 128
  const int N = (wi == 8) ? 512 : 128;           // w3 has N=512
  const int total = N << kshift;
  const int offs[10] = {0, 16384, 32768, 49152, 65536, 81920, 98304, 114688, 131072, 196608};
  const float sc = (wi == 0 || wi == 3) ? 0.25f : 1.0f;  // fold 1/sqrt(HD) into Wq
  const float* src = w.p[wi];
  short* d = dst + offs[wi];
  const int K = 1 << kshift;
  for (int idx = blockIdx.x * 256 + threadIdx.x; idx < total; idx += gridDim.x * 256) {
    const int n = idx >> kshift, k = idx & (K - 1);
    d[idx] = f2bf(src[k * N + n] * sc);
  }
}

// ---------------- fused 6-way QKV projection (MFMA) ----------------
// grid (M/16, 6), block 64. blockIdx.y: 0..2 self QKV (A=x_tgt),
// 3 cross Q (A=enc_out, quirk), 4..5 cross K/V (A=x_tgt).
__global__ __launch_bounds__(64) void qkv_kernel(const float* __restrict__ x_tgt,
                                                 const float* __restrict__ enc_out,
                                                 const short* __restrict__ wt,
                                                 short* __restrict__ Qs, short* __restrict__ Ks,
                                                 short* __restrict__ Vts,
                                                 short* __restrict__ Qc, short* __restrict__ Kc,
                                                 short* __restrict__ Vtc) {
  const int lane = threadIdx.x, quad = lane >> 4, l16 = lane & 15;
  const int mbase = blockIdx.x * 16;
  const int which = blockIdx.y;
  const int kind = which % 3;  // 0=Q,1=K,2=Vt
  const float* A = (which == 3) ? enc_out : x_tgt;
  const short* W = wt + which * 16384;
  short* Qb = (which < 3) ? Qs : Qc;
  short* Kb = (which < 3) ? Ks : Kc;
  short* Vtb = (which < 3) ? Vts : Vtc;

  floatx4 acc[8];
#pragma unroll
  for (int ct = 0; ct < 8; ct++) acc[ct] = (floatx4){0.f, 0.f, 0.f, 0.f};

#pragma unroll
  for (int ks = 0; ks < 4; ks++) {
    const float4* ar = (const float4*)&A[(size_t)(mbase + l16) * DD + ks * 32 + quad * 8];
    const frag8 af = cvt8(ar[0], ar[1]);
#pragma unroll
    for (int ct = 0; ct < 8; ct++) {
      const frag8 bf = *(const frag8*)&W[(ct * 16 + l16) * DD + ks * 32 + quad * 8];
      acc[ct] = __builtin_amdgcn_mfma_f32_16x16x32_bf16(af, bf, acc[ct], 0, 0, 0);
    }
  }

  const int b = mbase >> 11;
  const int sbase = (mbase & 2047) + quad * 4;
#pragma unroll
  for (int ct = 0; ct < 8; ct++) {
    const int n = ct * 16 + l16, h = n & 7, dci = n >> 3;
    const int bh = b * HH + h;
#pragma unroll
    for (int r = 0; r < 4; r++) {
      const int s = sbase + r;
      const short v = f2bf(acc[ct][r]);
      if (kind == 0)      Qb[((size_t)bh * SS + s) * HDIM + dci] = v;
      else if (kind == 1) Kb[((size_t)bh * SS + s) * HDIM + dci] = v;
      else                Vtb[((size_t)bh * HDIM + dci) * SS + s] = v;
    }
  }
}

// ---------------- MFMA flash attention, split-K 4-wave blocks ----------------
// grid (SS/16, BB*HH, 2), block 256 = 4 waves; wave w owns keys [w*512, w*512+512).
__global__ __launch_bounds__(256) void attn_mfma_kernel(
    const short* __restrict__ Qa, const short* __restrict__ Ka,
    const short* __restrict__ Vta, short* __restrict__ AMa,
    const short* __restrict__ Qc, const short* __restrict__ Kc,
    const short* __restrict__ Vtc, short* __restrict__ AMc) {
  const int t = threadIdx.x, wid = t >> 6, lane = t & 63;
  const int quad = lane >> 4, l16 = lane & 15;
  const int bh = blockIdx.y;
  const int qbase = blockIdx.x * 16;
  const int inst = blockIdx.z;
  const short* Q = inst ? Qc : Qa;
  const short* K = inst ? Kc : Ka;
  const short* Vt = inst ? Vtc : Vta;
  short* AM = inst ? AMc : AMa;
  const size_t headoff = (size_t)bh * SS;
  const int q = qbase + l16;

  __shared__ short sP[4][16 * SP_STRIDE];
  __shared__ float pnum[4][16 * 17];  // [wave][d*17+q] (pad 17)
  __shared__ float pl[4][16];

  // Q fragment: A[m=l16][k=quad*8+j]; quads 2,3 are the zero-padded K range.
  frag8 qf;
  if (quad < 2) qf = *(const frag8*)&Q[(headoff + q) * HDIM + quad * 8];
  else {
#pragma unroll
    for (int i = 0; i < 8; i++) qf[i] = 0;
  }

  frag8 onef;
#pragma unroll
  for (int i = 0; i < 8; i++) onef[i] = (short)0x3f80;  // bf16 1.0

  floatx4 acc_o = {0.f, 0.f, 0.f, 0.f};
  floatx4 acc_l = {0.f, 0.f, 0.f, 0.f};

#pragma unroll 2
  for (int kt = 0; kt < 8; kt++) {
    const int keybase = wid * 512 + kt * 64;
    floatx4 sc[4];
#pragma unroll
    for (int st = 0; st < 4; st++) {
      frag8 kf;
      if (quad < 2) kf = *(const frag8*)&K[(headoff + keybase + st * 16 + l16) * HDIM + quad * 8];
      else {
#pragma unroll
        for (int i = 0; i < 8; i++) kf[i] = 0;
      }
      const floatx4 z = {0.f, 0.f, 0.f, 0.f};
      sc[st] = __builtin_amdgcn_mfma_f32_16x16x32_bf16(qf, kf, z, 0, 0, 0);
    }
#pragma unroll
    for (int st = 0; st < 4; st++) {
#pragma unroll
      for (int r = 0; r < 4; r++) {
        sP[wid][(quad * 4 + r) * SP_STRIDE + st * 16 + l16] = f2bf(__expf(sc[st][r]));
      }
    }
#pragma unroll
    for (int w = 0; w < 2; w++) {
      const frag8 vf = *(const frag8*)&Vt[((size_t)bh * HDIM + l16) * SS + keybase + w * 32 + quad * 8];
      const frag8 pf = *(const frag8*)&sP[wid][l16 * SP_STRIDE + w * 32 + quad * 8];
      acc_o = __builtin_amdgcn_mfma_f32_16x16x32_bf16(vf, pf, acc_o, 0, 0, 0);
      acc_l = __builtin_amdgcn_mfma_f32_16x16x32_bf16(onef, pf, acc_l, 0, 0, 0);
    }
  }

#pragma unroll
  for (int r = 0; r < 4; r++) pnum[wid][(quad * 4 + r) * 17 + l16] = acc_o[r];
  if (quad == 0) pl[wid][l16] = acc_l[0];
  __syncthreads();

  {
    const int d = t >> 4, q16 = t & 15;
    const float num = pnum[0][d * 17 + q16] + pnum[1][d * 17 + q16] +
                      pnum[2][d * 17 + q16] + pnum[3][d * 17 + q16];
    const float l = pl[0][q16] + pl[1][q16] + pl[2][q16] + pl[3][q16];
    const int b = bh >> 3, h = bh & 7;
    AM[((size_t)b * SS + qbase + q16) * DD + d * 8 + h] = f2bf(num / l);
  }
}

// ---------------- fused residual GEMMs + norm ----------------
// R2 = AMs@w1 + AMc@w2 + b1 + b2 + x_tgt (fp32); LN = (R2-mean)/var (bf16).
// grid M/16, block 256 = 4 waves; wave w owns cols [w*32, w*32+32).
__global__ __launch_bounds__(256) void gemm12_norm_kernel(
    const short* __restrict__ AMs, const short* __restrict__ AMc,
    const short* __restrict__ W1, const short* __restrict__ W2,
    const float* __restrict__ b1, const float* __restrict__ b2,
    const float* __restrict__ x_tgt, float* __restrict__ R2,
    short* __restrict__ LN) {
  const int t = threadIdx.x, w = t >> 6, lane = t & 63;
  const int quad = lane >> 4, l16 = lane & 15;
  const int mbase = blockIdx.x * 16;

  __shared__ float sumS[4][16];
  __shared__ float sumQ[4][16];

  floatx4 acc[2];
  acc[0] = (floatx4){0.f, 0.f, 0.f, 0.f};
  acc[1] = (floatx4){0.f, 0.f, 0.f, 0.f};

#pragma unroll
  for (int ks = 0; ks < 4; ks++) {
    const frag8 afS = *(const frag8*)&AMs[(size_t)(mbase + l16) * DD + ks * 32 + quad * 8];
    const frag8 afC = *(const frag8*)&AMc[(size_t)(mbase + l16) * DD + ks * 32 + quad * 8];
#pragma unroll
    for (int c = 0; c < 2; c++) {
      const int n0 = (w * 2 + c) * 16 + l16;
      const frag8 bf1 = *(const frag8*)&W1[n0 * DD + ks * 32 + quad * 8];
      const frag8 bf2 = *(const frag8*)&W2[n0 * DD + ks * 32 + quad * 8];
      acc[c] = __builtin_amdgcn_mfma_f32_16x16x32_bf16(afS, bf1, acc[c], 0, 0, 0);
      acc[c] = __builtin_amdgcn_mfma_f32_16x16x32_bf16(afC, bf2, acc[c], 0, 0, 0);
    }
  }

  float v[2][4];
#pragma unroll
  for (int c = 0; c < 2; c++) {
    const int n = w * 32 + c * 16 + l16;
    const float bn = b1[n] + b2[n];
#pragma unroll
    for (int r = 0; r < 4; r++) {
      const int m = mbase + quad * 4 + r;
      v[c][r] = acc[c][r] + bn + x_tgt[(size_t)m * DD + n];
      R2[(size_t)m * DD + n] = v[c][r];
    }
  }

  // partial row sums over this wave's 32 cols (reduce across 16 l16 lanes)
#pragma unroll
  for (int r = 0; r < 4; r++) {
    float s = v[0][r] + v[1][r];
    float sq = v[0][r] * v[0][r] + v[1][r] * v[1][r];
#pragma unroll
    for (int mk = 1; mk < 16; mk <<= 1) {
      s += __shfl_xor(s, mk, 64);
      sq += __shfl_xor(sq, mk, 64);
    }
    if (l16 == 0) {
      sumS[w][quad * 4 + r] = s;
      sumQ[w][quad * 4 + r] = sq;
    }
  }
  __syncthreads();

#pragma unroll
  for (int r = 0; r < 4; r++) {
    const int row = quad * 4 + r;
    const float S = sumS[0][row] + sumS[1][row] + sumS[2][row] + sumS[3][row];
    const float Qs_ = sumQ[0][row] + sumQ[1][row] + sumQ[2][row] + sumQ[3][row];
    const float mean = S * (1.0f / 128.0f);
    const float cs = Qs_ - S * mean;        // sum of squared deviations
    const float ivar = 127.0f / cs;         // 1/var, var = cs/127 (faithful quirk)
    const int m = mbase + row;
#pragma unroll
    for (int c = 0; c < 2; c++) {
      const int n = w * 32 + c * 16 + l16;
      LN[(size_t)m * DD + n] = f2bf((v[c][r] - mean) * ivar);
    }
  }
}

// ---------------- fused FFN: out = relu(LN@W3+b3)@W4 + b4 + R2 ----------------
// grid M/16, block 256 = 4 waves. Phase1: wave w computes h cols [w*128,(w+1)*128)
// into LDS. Phase2: wave w computes out cols [w*32, w*32+32) over K=512 from LDS.
__global__ __launch_bounds__(256) void ffn_fused_kernel(
    const short* __restrict__ LN, const short* __restrict__ W3,
    const float* __restrict__ b3, const short* __restrict__ W4,
    const float* __restrict__ b4, const float* __restrict__ R2,
    float* __restrict__ Out) {
  const int t = threadIdx.x, w = t >> 6, lane = t & 63;
  const int quad = lane >> 4, l16 = lane & 15;
  const int mbase = blockIdx.x * 16;

  __shared__ short hs[16 * HS];  // 16 rows x 520 bf16

  // ---- phase 1: h = relu(LN @ W3 + b3), this wave's 128-col slab ----
  {
    floatx4 acc[8];
#pragma unroll
    for (int ct = 0; ct < 8; ct++) acc[ct] = (floatx4){0.f, 0.f, 0.f, 0.f};
    const int nblk = w * 128;
#pragma unroll
    for (int ks = 0; ks < 4; ks++) {
      const frag8 af = *(const frag8*)&LN[(size_t)(mbase + l16) * DD + ks * 32 + quad * 8];
#pragma unroll
      for (int ct = 0; ct < 8; ct++) {
        const frag8 bf = *(const frag8*)&W3[(size_t)(nblk + ct * 16 + l16) * DD + ks * 32 + quad * 8];
        acc[ct] = __builtin_amdgcn_mfma_f32_16x16x32_bf16(af, bf, acc[ct], 0, 0, 0);
      }
    }
#pragma unroll
    for (int ct = 0; ct < 8; ct++) {
      const int n = nblk + ct * 16 + l16;
      const float bn = b3[n];
#pragma unroll
      for (int r = 0; r < 4; r++) {
        hs[(quad * 4 + r) * HS + n] = f2bf(fmaxf(acc[ct][r] + bn, 0.f));
      }
    }
  }
  __syncthreads();

  // ---- phase 2: out = h @ W4 + b4 + R2, this wave's 32-col slice ----
  {
    floatx4 acc[2];
    acc[0] = (floatx4){0.f, 0.f, 0.f, 0.f};
    acc[1] = (floatx4){0.f, 0.f, 0.f, 0.f};
#pragma unroll 4
    for (int ks = 0; ks < 16; ks++) {
      const frag8 af = *(const frag8*)&hs[l16 * HS + ks * 32 + quad * 8];
#pragma unroll
      for (int c = 0; c < 2; c++) {
        const int n0 = w * 32 + c * 16 + l16;
        const frag8 bf = *(const frag8*)&W4[(size_t)n0 * DF + ks * 32 + quad * 8];
        acc[c] = __builtin_amdgcn_mfma_f32_16x16x32_bf16(af, bf, acc[c], 0, 0, 0);
      }
    }
#pragma unroll
    for (int c = 0; c < 2; c++) {
      const int n = w * 32 + c * 16 + l16;
      const float bn = b4[n];
#pragma unroll
      for (int r = 0; r < 4; r++) {
        const int m = mbase + quad * 4 + r;
        Out[(size_t)m * DD + n] = acc[c][r] + bn + R2[(size_t)m * DD + n];
      }
    }
  }
}

extern "C" void kernel_launch(void* const* d_in, const int* in_sizes, int n_in,
                              void* d_out, int out_size, void* d_ws, size_t ws_size,
                              hipStream_t stream) {
  (void)in_sizes; (void)n_in; (void)out_size; (void)ws_size;
  const float* x_tgt   = (const float*)d_in[0];
  const float* enc_out = (const float*)d_in[1];
  const float* b1 = (const float*)d_in[9];
  const float* b2 = (const float*)d_in[11];
  const float* b3 = (const float*)d_in[13];
  const float* b4 = (const float*)d_in[15];

  WSrc wsrc;
  wsrc.p[0] = (const float*)d_in[2];   // self_wq
  wsrc.p[1] = (const float*)d_in[3];   // self_wk
  wsrc.p[2] = (const float*)d_in[4];   // self_wv
  wsrc.p[3] = (const float*)d_in[5];   // cross_wq
  wsrc.p[4] = (const float*)d_in[6];   // cross_wk
  wsrc.p[5] = (const float*)d_in[7];   // cross_wv
  wsrc.p[6] = (const float*)d_in[8];   // w1
  wsrc.p[7] = (const float*)d_in[10];  // w2
  wsrc.p[8] = (const float*)d_in[12];  // w3
  wsrc.p[9] = (const float*)d_in[14];  // w4

  // workspace layout (float-slot offsets; bf16 buffers use 2 elems per slot)
  float* ws = (float*)d_ws;
  short* wt   = (short*)(ws + 0);          // 262144 bf16 (512 KB)
  short* Qs   = (short*)(ws + 131072);     // each QKV buf: 524288 bf16
  short* Ks   = (short*)(ws + 393216);
  short* Vts  = (short*)(ws + 655360);
  short* AMs  = (short*)(ws + 917504);
  short* Qc   = (short*)(ws + 1179648);
  short* Kc   = (short*)(ws + 1441792);
  short* Vtc  = (short*)(ws + 1703936);
  short* AMc  = (short*)(ws + 1966080);
  float* R2   = ws + 2228224;
  short* LN   = (short*)(ws + 2752512);    // 524288 bf16

  const int M = BB * SS;  // 4096
  const int MT = M / 16;  // 256 row-tiles

  wprep_kernel<<<dim3(64, 10), 256, 0, stream>>>(wsrc, wt);

  // all 6 projections in one launch (cross-Q reads enc_out — faithful quirk)
  qkv_kernel<<<dim3(MT, 6), 64, 0, stream>>>(x_tgt, enc_out, wt, Qs, Ks, Vts, Qc, Kc, Vtc);

  // both attentions in one launch; split-K 4-wave blocks
  attn_mfma_kernel<<<dim3(SS / 16, BB * HH, 2), 256, 0, stream>>>(
      Qs, Ks, Vts, AMs, Qc, Kc, Vtc, AMc);

  // fused residual GEMMs + norm (R1 never materialized)
  gemm12_norm_kernel<<<MT, 256, 0, stream>>>(AMs, AMc, wt + 98304, wt + 114688,
                                             b1, b2, x_tgt, R2, LN);

  // fused FFN (h never leaves LDS)
  ffn_fused_kernel<<<MT, 256, 0, stream>>>(LN, wt + 131072, b3, wt + 196608, b4,
                                           R2, (float*)d_out);
}

// Round 8
// 155.190 us; speedup vs baseline: 9.5925x; 1.2015x over previous
//
#include <hip/hip_runtime.h>
#include <hip/hip_bf16.h>

// Problem constants
#define BB 2
#define SS 2048
#define DD 128
#define HH 8
#define HDIM 16
#define DF 512
#define SPK 36        // attn P stride (shorts); 72B rows
#define HS 520        // ffn LDS h stride (512 + 8 pad)

typedef float floatx4 __attribute__((ext_vector_type(4)));
typedef float floatx16 __attribute__((ext_vector_type(16)));
typedef short frag8 __attribute__((ext_vector_type(8)));

__device__ __forceinline__ short f2bf(float x) {
  union { __hip_bfloat16 h; short s; } u;
  u.h = __float2bfloat16(x);
  return u.s;
}
__device__ __forceinline__ frag8 cvt8(const float4 a, const float4 b) {
  frag8 r;
  r[0] = f2bf(a.x); r[1] = f2bf(a.y); r[2] = f2bf(a.z); r[3] = f2bf(a.w);
  r[4] = f2bf(b.x); r[5] = f2bf(b.y); r[6] = f2bf(b.z); r[7] = f2bf(b.w);
  return r;
}

// ---------------- weight prep: WT[n][k] bf16, scale folded ----------------
struct WSrc { const float* p[10]; };
// order: self_wq,self_wk,self_wv,cross_wq,cross_wk,cross_wv,w1,w2,w3,w4
__global__ __launch_bounds__(256) void wprep_kernel(WSrc w, short* __restrict__ dst) {
  const int wi = blockIdx.y;
  const int kshift = (wi == 9) ? 9 : 7;          // K: 512 for w4, else 128
  const int N = (wi == 8) ? 512 : 128;           // w3 has N=512
  const int total = N << kshift;
  const int offs[10] = {0, 16384, 32768, 49152, 65536, 81920, 98304, 114688, 131072, 196608};
  const float sc = (wi == 0 || wi == 3) ? 0.25f : 1.0f;  // fold 1/sqrt(HD) into Wq
  const float* src = w.p[wi];
  short* d = dst + offs[wi];
  const int K = 1 << kshift;
  for (int idx = blockIdx.x * 256 + threadIdx.x; idx < total; idx += gridDim.x * 256) {
    const int n = idx >> kshift, k = idx & (K - 1);
    d[idx] = f2bf(src[k * N + n] * sc);
  }
}

// ---------------- fused 6-way QKV projection (MFMA) ----------------
// grid (M/16, 6), block 64. blockIdx.y: 0..2 self QKV (A=x_tgt),
// 3 cross Q (A=enc_out, quirk), 4..5 cross K/V (A=x_tgt).
// Epilogue stages C-tile in LDS, then writes coalesced b64 bursts.
__global__ __launch_bounds__(64) void qkv_kernel(const float* __restrict__ x_tgt,
                                                 const float* __restrict__ enc_out,
                                                 const short* __restrict__ wt,
                                                 short* __restrict__ Qs, short* __restrict__ Ks,
                                                 short* __restrict__ Vts,
                                                 short* __restrict__ Qc, short* __restrict__ Kc,
                                                 short* __restrict__ Vtc) {
  const int lane = threadIdx.x, quad = lane >> 4, l16 = lane & 15;
  const int mbase = blockIdx.x * 16;
  const int which = blockIdx.y;
  const int kind = which % 3;  // 0=Q,1=K,2=Vt
  const float* A = (which == 3) ? enc_out : x_tgt;
  const short* W = wt + which * 16384;
  short* Qb = (which < 3) ? Qs : Qc;
  short* Kb = (which < 3) ? Ks : Kc;
  short* Vtb = (which < 3) ? Vts : Vtc;

  __shared__ short sC[16 * 130];  // [m-local][n] bf16, stride 130

  floatx4 acc[8];
#pragma unroll
  for (int ct = 0; ct < 8; ct++) acc[ct] = (floatx4){0.f, 0.f, 0.f, 0.f};

#pragma unroll
  for (int ks = 0; ks < 4; ks++) {
    const float4* ar = (const float4*)&A[(size_t)(mbase + l16) * DD + ks * 32 + quad * 8];
    const frag8 af = cvt8(ar[0], ar[1]);
#pragma unroll
    for (int ct = 0; ct < 8; ct++) {
      const frag8 bf = *(const frag8*)&W[(ct * 16 + l16) * DD + ks * 32 + quad * 8];
      acc[ct] = __builtin_amdgcn_mfma_f32_16x16x32_bf16(af, bf, acc[ct], 0, 0, 0);
    }
  }

  // stage C tile: row m-local = quad*4+r, col n = ct*16+l16
#pragma unroll
  for (int ct = 0; ct < 8; ct++) {
#pragma unroll
    for (int r = 0; r < 4; r++) {
      sC[(quad * 4 + r) * 130 + ct * 16 + l16] = f2bf(acc[ct][r]);
    }
  }
  // single wave per block: compiler's lgkmcnt ordering suffices (no barrier)

  const int b = mbase >> 11;
  const int sbase = mbase & 2047;
  if (kind <= 1) {
    short* Dst = (kind == 0) ? Qb : Kb;
    const int s = lane >> 2, c4 = lane & 3;
#pragma unroll
    for (int h = 0; h < 8; h++) {
      short4 v;  // split quirk: n = dci*8 + h
      v.x = sC[s * 130 + (c4 * 4 + 0) * 8 + h];
      v.y = sC[s * 130 + (c4 * 4 + 1) * 8 + h];
      v.z = sC[s * 130 + (c4 * 4 + 2) * 8 + h];
      v.w = sC[s * 130 + (c4 * 4 + 3) * 8 + h];
      const int bh = b * HH + h;
      *(short4*)&Dst[((size_t)bh * SS + sbase + s) * HDIM + c4 * 4] = v;
    }
  } else {
    const int dci = lane >> 2, c4 = lane & 3;
#pragma unroll
    for (int h = 0; h < 8; h++) {
      short4 v;
      v.x = sC[(c4 * 4 + 0) * 130 + dci * 8 + h];
      v.y = sC[(c4 * 4 + 1) * 130 + dci * 8 + h];
      v.z = sC[(c4 * 4 + 2) * 130 + dci * 8 + h];
      v.w = sC[(c4 * 4 + 3) * 130 + dci * 8 + h];
      const int bh = b * HH + h;
      *(short4*)&Vtb[((size_t)bh * HDIM + dci) * SS + sbase + c4 * 4] = v;
    }
  }
}

// ---------------- MFMA flash attention: 32x32x16 QK, split-K 4-wave blocks ----
// grid (SS/32, BB*HH, 2), block 256 = 4 waves; wave w owns keys [w*512, w*512+512)
// for the block's 32 queries. QK computes C[key][query] (full density, K=HD=16);
// P packs to b64 LDS writes in [q][key] layout, which PV reads as b128 B-frags.
__global__ __launch_bounds__(256) void attn_mfma_kernel(
    const short* __restrict__ Qa, const short* __restrict__ Ka,
    const short* __restrict__ Vta, short* __restrict__ AMa,
    const short* __restrict__ Qc, const short* __restrict__ Kc,
    const short* __restrict__ Vtc, short* __restrict__ AMc) {
  const int t = threadIdx.x, wid = t >> 6, lane = t & 63;
  const int l32 = lane & 31, half = lane >> 5;   // 32-wide frag coords
  const int quad = (lane >> 4) & 3, l16 = lane & 15;
  const int bh = blockIdx.y;
  const int qbase = blockIdx.x * 32;
  const int inst = blockIdx.z;
  const short* Q = inst ? Qc : Qa;
  const short* K = inst ? Kc : Ka;
  const short* Vt = inst ? Vtc : Vta;
  short* AM = inst ? AMc : AMa;
  const size_t headoff = (size_t)bh * SS;

  __shared__ short sP[4][32 * SPK];   // [wave][q][key(32)] bf16
  __shared__ float pnum[4][16 * 33];  // [wave][d*33+q]
  __shared__ float pl[4][32];

  // Q B-frag (32x32x16): n=q=l32, k=half*8+j  (Q pre-scaled by 1/sqrt(HD))
  const frag8 qf = *(const frag8*)&Q[(headoff + qbase + l32) * HDIM + half * 8];

  frag8 onef;
#pragma unroll
  for (int i = 0; i < 8; i++) onef[i] = (short)0x3f80;  // bf16 1.0

  floatx4 acc_o[2], acc_l[2];
  acc_o[0] = (floatx4){0.f, 0.f, 0.f, 0.f}; acc_o[1] = acc_o[0];
  acc_l[0] = acc_o[0]; acc_l[1] = acc_o[0];

  const int keyw = wid * 512;
#pragma unroll 1
  for (int it = 0; it < 16; it++) {
    const int kb = keyw + it * 32;
    // K A-frag: m=key=l32, k=half*8+j — branchless b128
    const frag8 kf = *(const frag8*)&K[(headoff + kb + l32) * HDIM + half * 8];
    const floatx16 z16 = {0.f};
    // C[m=key][n=q]: col=lane&31=q, row=key=(reg&3)+8*(reg>>2)+4*half
    const floatx16 sc = __builtin_amdgcn_mfma_f32_32x32x16_bf16(kf, qf, z16, 0, 0, 0);
    // exp + pack: reg group g (regs 4g..4g+3) = keys 8g+4*half+0..3 at fixed q=l32
#pragma unroll
    for (int g = 0; g < 4; g++) {
      short4 pk;
      pk.x = f2bf(__expf(sc[4 * g + 0]));
      pk.y = f2bf(__expf(sc[4 * g + 1]));
      pk.z = f2bf(__expf(sc[4 * g + 2]));
      pk.w = f2bf(__expf(sc[4 * g + 3]));
      *(short4*)&sP[wid][l32 * SPK + g * 8 + half * 4] = pk;
    }
    // PV (operand-swapped, 16x16x32): C[d][q'] += Vt(16d x 32k) @ P^T(32k x 16q')
#pragma unroll
    for (int qh = 0; qh < 2; qh++) {
      const frag8 pf = *(const frag8*)&sP[wid][(qh * 16 + l16) * SPK + quad * 8];
      const frag8 vf = *(const frag8*)&Vt[((size_t)bh * HDIM + l16) * SS + kb + quad * 8];
      acc_o[qh] = __builtin_amdgcn_mfma_f32_16x16x32_bf16(vf, pf, acc_o[qh], 0, 0, 0);
      acc_l[qh] = __builtin_amdgcn_mfma_f32_16x16x32_bf16(onef, pf, acc_l[qh], 0, 0, 0);
    }
  }

  // stage per-wave partials: acc_o[qh] reg r = num[d=quad*4+r][q=qh*16+l16]
#pragma unroll
  for (int qh = 0; qh < 2; qh++) {
#pragma unroll
    for (int r = 0; r < 4; r++) {
      pnum[wid][(quad * 4 + r) * 33 + qh * 16 + l16] = acc_o[qh][r];
    }
    if (quad == 0) pl[wid][qh * 16 + l16] = acc_l[qh][0];  // rows replicated
  }
  __syncthreads();

  // combine 4 k-split waves: 512 outputs (32q x 16d)
  {
    const int b = bh >> 3, h = bh & 7;
#pragma unroll
    for (int idx = t; idx < 512; idx += 256) {
      const int q16 = idx & 31, d = idx >> 5;
      const float num = pnum[0][d * 33 + q16] + pnum[1][d * 33 + q16] +
                        pnum[2][d * 33 + q16] + pnum[3][d * 33 + q16];
      const float l = pl[0][q16] + pl[1][q16] + pl[2][q16] + pl[3][q16];
      AM[((size_t)b * SS + qbase + q16) * DD + d * 8 + h] = f2bf(num / l);
    }
  }
}

// ---------------- fused residual GEMMs + norm ----------------
// R2 = AMs@w1 + AMc@w2 + b1 + b2 + x_tgt (fp32); LN = (R2-mean)/var (bf16).
// grid M/16, block 256 = 4 waves; wave w owns cols [w*32, w*32+32).
__global__ __launch_bounds__(256) void gemm12_norm_kernel(
    const short* __restrict__ AMs, const short* __restrict__ AMc,
    const short* __restrict__ W1, const short* __restrict__ W2,
    const float* __restrict__ b1, const float* __restrict__ b2,
    const float* __restrict__ x_tgt, float* __restrict__ R2,
    short* __restrict__ LN) {
  const int t = threadIdx.x, w = t >> 6, lane = t & 63;
  const int quad = lane >> 4, l16 = lane & 15;
  const int mbase = blockIdx.x * 16;

  __shared__ float sumS[4][16];
  __shared__ float sumQ[4][16];

  floatx4 acc[2];
  acc[0] = (floatx4){0.f, 0.f, 0.f, 0.f};
  acc[1] = (floatx4){0.f, 0.f, 0.f, 0.f};

#pragma unroll
  for (int ks = 0; ks < 4; ks++) {
    const frag8 afS = *(const frag8*)&AMs[(size_t)(mbase + l16) * DD + ks * 32 + quad * 8];
    const frag8 afC = *(const frag8*)&AMc[(size_t)(mbase + l16) * DD + ks * 32 + quad * 8];
#pragma unroll
    for (int c = 0; c < 2; c++) {
      const int n0 = (w * 2 + c) * 16 + l16;
      const frag8 bf1 = *(const frag8*)&W1[n0 * DD + ks * 32 + quad * 8];
      const frag8 bf2 = *(const frag8*)&W2[n0 * DD + ks * 32 + quad * 8];
      acc[c] = __builtin_amdgcn_mfma_f32_16x16x32_bf16(afS, bf1, acc[c], 0, 0, 0);
      acc[c] = __builtin_amdgcn_mfma_f32_16x16x32_bf16(afC, bf2, acc[c], 0, 0, 0);
    }
  }

  float v[2][4];
#pragma unroll
  for (int c = 0; c < 2; c++) {
    const int n = w * 32 + c * 16 + l16;
    const float bn = b1[n] + b2[n];
#pragma unroll
    for (int r = 0; r < 4; r++) {
      const int m = mbase + quad * 4 + r;
      v[c][r] = acc[c][r] + bn + x_tgt[(size_t)m * DD + n];
      R2[(size_t)m * DD + n] = v[c][r];
    }
  }

#pragma unroll
  for (int r = 0; r < 4; r++) {
    float s = v[0][r] + v[1][r];
    float sq = v[0][r] * v[0][r] + v[1][r] * v[1][r];
#pragma unroll
    for (int mk = 1; mk < 16; mk <<= 1) {
      s += __shfl_xor(s, mk, 64);
      sq += __shfl_xor(sq, mk, 64);
    }
    if (l16 == 0) {
      sumS[w][quad * 4 + r] = s;
      sumQ[w][quad * 4 + r] = sq;
    }
  }
  __syncthreads();

#pragma unroll
  for (int r = 0; r < 4; r++) {
    const int row = quad * 4 + r;
    const float S = sumS[0][row] + sumS[1][row] + sumS[2][row] + sumS[3][row];
    const float Qs_ = sumQ[0][row] + sumQ[1][row] + sumQ[2][row] + sumQ[3][row];
    const float mean = S * (1.0f / 128.0f);
    const float cs = Qs_ - S * mean;        // sum of squared deviations
    const float ivar = 127.0f / cs;         // 1/var, var = cs/127 (faithful quirk)
    const int m = mbase + row;
#pragma unroll
    for (int c = 0; c < 2; c++) {
      const int n = w * 32 + c * 16 + l16;
      LN[(size_t)m * DD + n] = f2bf((v[c][r] - mean) * ivar);
    }
  }
}

// ---------------- fused FFN: out = relu(LN@W3+b3)@W4 + b4 + R2 ----------------
// grid M/16, block 256 = 4 waves. Phase1: wave w computes h cols [w*128,(w+1)*128)
// into LDS. Phase2: wave w computes out cols [w*32, w*32+32) over K=512 from LDS.
__global__ __launch_bounds__(256) void ffn_fused_kernel(
    const short* __restrict__ LN, const short* __restrict__ W3,
    const float* __restrict__ b3, const short* __restrict__ W4,
    const float* __restrict__ b4, const float* __restrict__ R2,
    float* __restrict__ Out) {
  const int t = threadIdx.x, w = t >> 6, lane = t & 63;
  const int quad = lane >> 4, l16 = lane & 15;
  const int mbase = blockIdx.x * 16;

  __shared__ short hs[16 * HS];  // 16 rows x 520 bf16

  {
    floatx4 acc[8];
#pragma unroll
    for (int ct = 0; ct < 8; ct++) acc[ct] = (floatx4){0.f, 0.f, 0.f, 0.f};
    const int nblk = w * 128;
#pragma unroll
    for (int ks = 0; ks < 4; ks++) {
      const frag8 af = *(const frag8*)&LN[(size_t)(mbase + l16) * DD + ks * 32 + quad * 8];
#pragma unroll
      for (int ct = 0; ct < 8; ct++) {
        const frag8 bf = *(const frag8*)&W3[(size_t)(nblk + ct * 16 + l16) * DD + ks * 32 + quad * 8];
        acc[ct] = __builtin_amdgcn_mfma_f32_16x16x32_bf16(af, bf, acc[ct], 0, 0, 0);
      }
    }
#pragma unroll
    for (int ct = 0; ct < 8; ct++) {
      const int n = nblk + ct * 16 + l16;
      const float bn = b3[n];
#pragma unroll
      for (int r = 0; r < 4; r++) {
        hs[(quad * 4 + r) * HS + n] = f2bf(fmaxf(acc[ct][r] + bn, 0.f));
      }
    }
  }
  __syncthreads();

  {
    floatx4 acc[2];
    acc[0] = (floatx4){0.f, 0.f, 0.f, 0.f};
    acc[1] = (floatx4){0.f, 0.f, 0.f, 0.f};
#pragma unroll 4
    for (int ks = 0; ks < 16; ks++) {
      const frag8 af = *(const frag8*)&hs[l16 * HS + ks * 32 + quad * 8];
#pragma unroll
      for (int c = 0; c < 2; c++) {
        const int n0 = w * 32 + c * 16 + l16;
        const frag8 bf = *(const frag8*)&W4[(size_t)n0 * DF + ks * 32 + quad * 8];
        acc[c] = __builtin_amdgcn_mfma_f32_16x16x32_bf16(af, bf, acc[c], 0, 0, 0);
      }
    }
#pragma unroll
    for (int c = 0; c < 2; c++) {
      const int n = w * 32 + c * 16 + l16;
      const float bn = b4[n];
#pragma unroll
      for (int r = 0; r < 4; r++) {
        const int m = mbase + quad * 4 + r;
        Out[(size_t)m * DD + n] = acc[c][r] + bn + R2[(size_t)m * DD + n];
      }
    }
  }
}

extern "C" void kernel_launch(void* const* d_in, const int* in_sizes, int n_in,
                              void* d_out, int out_size, void* d_ws, size_t ws_size,
                              hipStream_t stream) {
  (void)in_sizes; (void)n_in; (void)out_size; (void)ws_size;
  const float* x_tgt   = (const float*)d_in[0];
  const float* enc_out = (const float*)d_in[1];
  const float* b1 = (const float*)d_in[9];
  const float* b2 = (const float*)d_in[11];
  const float* b3 = (const float*)d_in[13];
  const float* b4 = (const float*)d_in[15];

  WSrc wsrc;
  wsrc.p[0] = (const float*)d_in[2];   // self_wq
  wsrc.p[1] = (const float*)d_in[3];   // self_wk
  wsrc.p[2] = (const float*)d_in[4];   // self_wv
  wsrc.p[3] = (const float*)d_in[5];   // cross_wq
  wsrc.p[4] = (const float*)d_in[6];   // cross_wk
  wsrc.p[5] = (const float*)d_in[7];   // cross_wv
  wsrc.p[6] = (const float*)d_in[8];   // w1
  wsrc.p[7] = (const float*)d_in[10];  // w2
  wsrc.p[8] = (const float*)d_in[12];  // w3
  wsrc.p[9] = (const float*)d_in[14];  // w4

  // workspace layout (float-slot offsets; bf16 buffers use 2 elems per slot)
  float* ws = (float*)d_ws;
  short* wt   = (short*)(ws + 0);          // 262144 bf16 (512 KB)
  short* Qs   = (short*)(ws + 131072);     // each QKV buf: 524288 bf16
  short* Ks   = (short*)(ws + 393216);
  short* Vts  = (short*)(ws + 655360);
  short* AMs  = (short*)(ws + 917504);
  short* Qc   = (short*)(ws + 1179648);
  short* Kc   = (short*)(ws + 1441792);
  short* Vtc  = (short*)(ws + 1703936);
  short* AMc  = (short*)(ws + 1966080);
  float* R2   = ws + 2228224;
  short* LN   = (short*)(ws + 2752512);    // 524288 bf16

  const int M = BB * SS;  // 4096
  const int MT = M / 16;  // 256 row-tiles

  wprep_kernel<<<dim3(64, 10), 256, 0, stream>>>(wsrc, wt);

  // all 6 projections in one launch (cross-Q reads enc_out — faithful quirk)
  qkv_kernel<<<dim3(MT, 6), 64, 0, stream>>>(x_tgt, enc_out, wt, Qs, Ks, Vts, Qc, Kc, Vtc);

  // both attentions in one launch; 32-query waves, split-K 4-wave blocks
  attn_mfma_kernel<<<dim3(SS / 32, BB * HH, 2), 256, 0, stream>>>(
      Qs, Ks, Vts, AMs, Qc, Kc, Vtc, AMc);

  // fused residual GEMMs + norm (R1 never materialized)
  gemm12_norm_kernel<<<MT, 256, 0, stream>>>(AMs, AMc, wt + 98304, wt + 114688,
                                             b1, b2, x_tgt, R2, LN);

  // fused FFN (h never leaves LDS)
  ffn_fused_kernel<<<MT, 256, 0, stream>>>(LN, wt + 131072, b3, wt + 196608, b4,
                                           R2, (float*)d_out);
}